// Round 13
// baseline (427.556 us; speedup 1.0000x reference)
//
#include <hip/hip_runtime.h>

#define N_NODES 50000
#define NPAD    50048   // padded row count (multiple of 64) so 32-row tiles need no guard
#define E_EDGES 800000
#define DIN 256
#define H 128
#define DOUT 64
#define EPSF 1e-5f
#define NBLK 196   // ceil(N_NODES/256)
#define RT   1563  // ceil(N_NODES/32) row tiles

typedef __bf16 bf16x8 __attribute__((ext_vector_type(8)));
typedef float  f32x4  __attribute__((ext_vector_type(4)));
typedef float  f32x2  __attribute__((ext_vector_type(2)));
typedef unsigned short ushort_t;
typedef unsigned int   uint_t;

#define L2E 1.4426950408889634f
#define LN2 0.6931471805599453f

#if __has_builtin(__builtin_amdgcn_exp2f)
#define EXP2F(x) __builtin_amdgcn_exp2f(x)
#else
#define EXP2F(x) __expf((x) * LN2)
#endif

__device__ inline float bf2f(uint_t u) {
    union { uint_t i; float f; } v; v.i = u << 16; return v.f;
}
__device__ inline ushort_t f2bf(float f) {
    uint_t u = __float_as_uint(f);
    uint_t r = (u + 0x7fffu + ((u >> 16) & 1u)) >> 16;
    return (ushort_t)r;
}

// ---- packed fp32 VOP3P helpers: explicit op_sel, trans-safe variants ----
__device__ __forceinline__ f32x2 pk_add(f32x2 a, f32x2 b) {
    f32x2 d;
    asm("v_pk_add_f32 %0, %1, %2 op_sel:[0,0] op_sel_hi:[1,1]"
        : "=v"(d) : "v"(a), "v"(b));
    return d;
}
// consumer of a trans-op (v_exp/v_rcp) result: 2 guaranteed wait states first
__device__ __forceinline__ f32x2 pk_add_tr(f32x2 a, f32x2 b) {
    f32x2 d;
    asm("s_nop 1\n\tv_pk_add_f32 %0, %1, %2 op_sel:[0,0] op_sel_hi:[1,1]"
        : "=v"(d) : "v"(a), "v"(b));
    return d;
}
__device__ __forceinline__ f32x2 pk_fma(f32x2 a, f32x2 b, f32x2 c) {
    f32x2 d;
    asm("v_pk_fma_f32 %0, %1, %2, %3 op_sel:[0,0,0] op_sel_hi:[1,1,1]"
        : "=v"(d) : "v"(a), "v"(b), "v"(c));
    return d;
}
__device__ __forceinline__ f32x2 pk_fma_tr(f32x2 a, f32x2 b, f32x2 c) {
    f32x2 d;
    asm("s_nop 1\n\tv_pk_fma_f32 %0, %1, %2, %3 op_sel:[0,0,0] op_sel_hi:[1,1,1]"
        : "=v"(d) : "v"(a), "v"(b), "v"(c));
    return d;
}

// ---- fp8 e4m3 helpers (hw path + software fallback) ----
#if __has_builtin(__builtin_amdgcn_cvt_f32_fp8)
#define FP8DEC(u, s) __builtin_amdgcn_cvt_f32_fp8((uint_t)(u), (s))
#else
__device__ inline float fp8_dec_sw(uint_t b) {
    uint_t s = (b & 0x80u) << 24;
    uint_t em = b & 0x7fu;
    if (em < 8u) return __uint_as_float(s);           // FTZ denormals
    uint_t ex = (em >> 3) + 120u;
    uint_t mn = (em & 7u) << 20;
    return __uint_as_float(s | (ex << 23) | mn);
}
#define FP8DEC(u, s) fp8_dec_sw(((uint_t)(u) >> (8 * (s))) & 0xffu)
#endif

// paired fp8 decode: 2 fp8 (low 16 bits) -> 2 floats
#if __has_builtin(__builtin_amdgcn_cvt_pk_f32_fp8)
__device__ __forceinline__ f32x2 cvtpk_q(uint_t u) {
    auto r = __builtin_amdgcn_cvt_pk_f32_fp8(u, false);
    f32x2 o; o.x = r[0]; o.y = r[1]; return o;
}
#else
__device__ __forceinline__ f32x2 cvtpk_q(uint_t u) {
    f32x2 r; r.x = FP8DEC(u, 0); r.y = FP8DEC(u, 1); return r;
}
#endif

#if __has_builtin(__builtin_amdgcn_cvt_pk_fp8_f32)
__device__ inline uint_t fp8_pk(float a, float b) {
    return (uint_t)__builtin_amdgcn_cvt_pk_fp8_f32(a, b, 0, false) & 0xffffu;
}
#else
__device__ inline uint_t fp8_enc_sw(float f) {
    uint_t u = __float_as_uint(f);
    uint_t s = (u >> 24) & 0x80u;
    uint_t a = u & 0x7fffffffu;
    if (a < 0x3c800000u) return s;           // |f| < 2^-6 -> 0
    if (a > 0x43e00000u) a = 0x43e00000u;    // clamp to 448
    uint_t r = a + 0x7ffffu + ((a >> 20) & 1u);
    uint_t ex = (r >> 23) - 120u;
    uint_t mn = (r >> 20) & 7u;
    return s | (ex << 3) | mn;
}
__device__ inline uint_t fp8_pk(float a, float b) {
    return fp8_enc_sw(a) | (fp8_enc_sw(b) << 8);
}
#endif

// ---------------- x -> bf16 ----------------
__global__ __launch_bounds__(256) void k_convx(const float* __restrict__ x, ushort_t* __restrict__ xb)
{
    int i = blockIdx.x * 256 + threadIdx.x;
    float4 v = ((const float4*)x)[i];
    ushort4 o;
    o.x = f2bf(v.x); o.y = f2bf(v.y); o.z = f2bf(v.z); o.w = f2bf(v.w);
    ((ushort4*)xb)[i] = o;
}

// ----------- merged weight packing (B^T layouts) -----------
__global__ __launch_bounds__(256) void k_pack(const float* __restrict__ Wk, const float* __restrict__ Wq,
                                              const float* __restrict__ Wv, const float* __restrict__ Ws,
                                              const float* __restrict__ W_in, const float* __restrict__ W_out,
                                              ushort_t* __restrict__ Bq, ushort_t* __restrict__ Bin,
                                              ushort_t* __restrict__ Bout)
{
    int t = blockIdx.x * 256 + threadIdx.x;
    if (t < 196608) {
        int l = t >> 16;
        int r = t & 65535;
        int c = r >> 7;
        int k = r & 127;
        int m = c >> 7;
        int cm = c & 127;
        const float* W = (m == 0) ? Wk : (m == 1) ? Wq : (m == 2) ? Wv : Ws;
        Bq[t] = f2bf(W[(size_t)l * H * H + k * H + cm]);
    } else if (t < 229376) {
        int t2 = t - 196608;
        int c = t2 >> 8;
        int k = t2 & 255;
        Bin[t2] = f2bf(W_in[k * H + c]);
    } else {
        int t3 = t - 229376;
        int c = t3 >> 7;
        int k = t3 & 127;
        Bout[t3] = f2bf(W_out[k * DOUT + c]);
    }
}

// ---------------- in_proj MFMA: h = bf16(x @ W_in + b_in) ----------------
__global__ __launch_bounds__(256) void k_in_mfma(const ushort_t* __restrict__ xb,
                                                 const ushort_t* __restrict__ Bin,
                                                 const float* __restrict__ b_in,
                                                 ushort_t* __restrict__ hb)
{
    int gw = blockIdx.x * 4 + (threadIdx.x >> 6);
    int lane = threadIdx.x & 63;
    int rt = gw >> 2, c32 = (gw & 3) * 32;
    int r0 = rt * 32;
    const ushort_t* Ap = xb + (size_t)(r0 + (lane & 15)) * DIN + 8 * (lane >> 4);
    const ushort_t* Bp = Bin + (size_t)(c32 + (lane & 15)) * DIN + 8 * (lane >> 4);
    f32x4 acc[2][2]; // [rb][nf]
    #pragma unroll
    for (int rb = 0; rb < 2; ++rb)
        #pragma unroll
        for (int nf = 0; nf < 2; ++nf) acc[rb][nf] = (f32x4){0.f, 0.f, 0.f, 0.f};
    #pragma unroll
    for (int ks = 0; ks < 8; ++ks) {
        bf16x8 a0 = *(const bf16x8*)(Ap + ks * 32);
        bf16x8 a1 = *(const bf16x8*)(Ap + 16 * DIN + ks * 32);
        bf16x8 b0 = *(const bf16x8*)(Bp + ks * 32);
        bf16x8 b1 = *(const bf16x8*)(Bp + 16 * DIN + ks * 32);
        acc[0][0] = __builtin_amdgcn_mfma_f32_16x16x32_bf16(a0, b0, acc[0][0], 0, 0, 0);
        acc[1][0] = __builtin_amdgcn_mfma_f32_16x16x32_bf16(a1, b0, acc[1][0], 0, 0, 0);
        acc[0][1] = __builtin_amdgcn_mfma_f32_16x16x32_bf16(a0, b1, acc[0][1], 0, 0, 0);
        acc[1][1] = __builtin_amdgcn_mfma_f32_16x16x32_bf16(a1, b1, acc[1][1], 0, 0, 0);
    }
    int rowoff = (lane >> 4) << 2;
    #pragma unroll
    for (int nf = 0; nf < 2; ++nf) {
        int col = c32 + nf * 16 + (lane & 15);
        float bb = b_in[col];
        #pragma unroll
        for (int rb = 0; rb < 2; ++rb)
            #pragma unroll
            for (int j = 0; j < 4; ++j)
                hb[(size_t)(r0 + rb * 16 + rowoff + j) * H + col] = f2bf(acc[rb][nf][j] + bb);
    }
}

// ------ qkvs MFMA ------
// pair 0 -> qf8 (fp8 q', 2/ushort) + vb (2 bf16 v / uint), entry e={f, f+16}
// pair 1 -> ks (uint: hi=agg bf16, lo=k' bf16), standard col index
__global__ __launch_bounds__(256) void k_qkvs_mfma(const ushort_t* __restrict__ hb,
                                                   const ushort_t* __restrict__ Bq, // [512][128]
                                                   const float* __restrict__ bk, const float* __restrict__ bq,
                                                   const float* __restrict__ bv, const float* __restrict__ bs,
                                                   ushort_t* __restrict__ qf8, uint_t* __restrict__ vb,
                                                   uint_t* __restrict__ ks)
{
    int gw = blockIdx.x * 4 + (threadIdx.x >> 6);
    int lane = threadIdx.x & 63;
    int rt = gw >> 3, cfg = gw & 7;
    int pair = cfg >> 2, c32 = (cfg & 3) * 32;
    int r0 = rt * 32;
    const ushort_t* Ap = hb + (size_t)(r0 + (lane & 15)) * H + 8 * (lane >> 4);
    int cb0 = pair ? 0   : 128;   // k : q
    int cb1 = pair ? 384 : 256;   // s : v
    const ushort_t* Bp0 = Bq + (size_t)(cb0 + c32 + (lane & 15)) * H + 8 * (lane >> 4);
    const ushort_t* Bp1 = Bq + (size_t)(cb1 + c32 + (lane & 15)) * H + 8 * (lane >> 4);
    f32x4 acc[2][2][2]; // [rb][mat][nf]
    #pragma unroll
    for (int rb = 0; rb < 2; ++rb)
        #pragma unroll
        for (int m = 0; m < 2; ++m)
            #pragma unroll
            for (int nf = 0; nf < 2; ++nf) acc[rb][m][nf] = (f32x4){0.f, 0.f, 0.f, 0.f};
    #pragma unroll
    for (int kk = 0; kk < 4; ++kk) {
        bf16x8 a0 = *(const bf16x8*)(Ap + kk * 32);
        bf16x8 a1 = *(const bf16x8*)(Ap + 16 * H + kk * 32);
        #pragma unroll
        for (int nf = 0; nf < 2; ++nf) {
            bf16x8 b0 = *(const bf16x8*)(Bp0 + nf * 16 * H + kk * 32);
            bf16x8 b1 = *(const bf16x8*)(Bp1 + nf * 16 * H + kk * 32);
            acc[0][0][nf] = __builtin_amdgcn_mfma_f32_16x16x32_bf16(a0, b0, acc[0][0][nf], 0, 0, 0);
            acc[1][0][nf] = __builtin_amdgcn_mfma_f32_16x16x32_bf16(a1, b0, acc[1][0][nf], 0, 0, 0);
            acc[0][1][nf] = __builtin_amdgcn_mfma_f32_16x16x32_bf16(a0, b1, acc[0][1][nf], 0, 0, 0);
            acc[1][1][nf] = __builtin_amdgcn_mfma_f32_16x16x32_bf16(a1, b1, acc[1][1][nf], 0, 0, 0);
        }
    }
    int rowoff = (lane >> 4) << 2;
    int l15 = lane & 15;
    if (pair == 0) {
        int col_lo = c32 + l15, col_hi = col_lo + 16;
        int e = (c32 >> 1) + l15;
        float bql = bq[col_lo], bqh = bq[col_hi];
        float bvl = bv[col_lo], bvh = bv[col_hi];
        #pragma unroll
        for (int rb = 0; rb < 2; ++rb)
            #pragma unroll
            for (int j = 0; j < 4; ++j) {
                size_t row = r0 + rb * 16 + rowoff + j;
                float ql = (acc[rb][0][0][j] + bql) * L2E;
                float qh = (acc[rb][0][1][j] + bqh) * L2E;
                qf8[row * 64 + e] = (ushort_t)fp8_pk(ql, qh);
                uint_t vl = f2bf(acc[rb][1][0][j] + bvl);
                uint_t vh = f2bf(acc[rb][1][1][j] + bvh);
                vb[row * 64 + e] = (vh << 16) | vl;
            }
    } else {
        #pragma unroll
        for (int nf = 0; nf < 2; ++nf) {
            int col = c32 + nf * 16 + l15;
            float bbk = bk[col], bbs = bs[col];
            #pragma unroll
            for (int rb = 0; rb < 2; ++rb)
                #pragma unroll
                for (int j = 0; j < 4; ++j) {
                    size_t row = r0 + rb * 16 + rowoff + j;
                    uint_t kkv = f2bf((acc[rb][0][nf][j] + bbk) * L2E);
                    uint_t ssv = f2bf(acc[rb][1][nf][j] + bbs);
                    ks[row * H + col] = (ssv << 16) | kkv;
                }
        }
    }
}

// ================= CSR build =================
__global__ __launch_bounds__(256) void k_hist(const int* __restrict__ ei, int* __restrict__ deg)
{
    int e = blockIdx.x * 256 + threadIdx.x;
    int dst = ei[E_EDGES + e];
    atomicAdd(&deg[dst], 1);
}

__global__ __launch_bounds__(256) void k_bsum(const int* __restrict__ deg, int* __restrict__ bsum)
{
    __shared__ int ws[4];
    int t = threadIdx.x;
    int i = blockIdx.x * 256 + t;
    int v = (i < N_NODES) ? deg[i] : 0;
    #pragma unroll
    for (int off = 32; off > 0; off >>= 1) v += __shfl_down(v, off);
    if ((t & 63) == 0) ws[t >> 6] = v;
    __syncthreads();
    if (t == 0) bsum[blockIdx.x] = ws[0] + ws[1] + ws[2] + ws[3];
}

__global__ __launch_bounds__(256) void k_bscan(const int* __restrict__ bsum, int* __restrict__ boff)
{
    __shared__ int ws[4];
    int t = threadIdx.x;
    int v = (t < NBLK) ? bsum[t] : 0;
    int lane = t & 63, wid = t >> 6;
    int inc = v;
    #pragma unroll
    for (int off = 1; off < 64; off <<= 1) {
        int u = __shfl_up(inc, off);
        if (lane >= off) inc += u;
    }
    if (lane == 63) ws[wid] = inc;
    __syncthreads();
    if (t == 0) {
        int s = 0;
        #pragma unroll
        for (int w = 0; w < 4; ++w) { int x = ws[w]; ws[w] = s; s += x; }
    }
    __syncthreads();
    if (t < NBLK) boff[t] = inc - v + ws[wid];
}

__global__ __launch_bounds__(256) void k_rowptr(const int* __restrict__ deg,
                                                const int* __restrict__ boff,
                                                int* __restrict__ rowptr)
{
    __shared__ int ws[4];
    int t = threadIdx.x;
    int i = blockIdx.x * 256 + t;
    int v = (i < N_NODES) ? deg[i] : 0;
    int lane = t & 63, wid = t >> 6;
    int inc = v;
    #pragma unroll
    for (int off = 1; off < 64; off <<= 1) {
        int u = __shfl_up(inc, off);
        if (lane >= off) inc += u;
    }
    if (lane == 63) ws[wid] = inc;
    __syncthreads();
    if (t == 0) {
        int s = 0;
        #pragma unroll
        for (int w = 0; w < 4; ++w) { int x = ws[w]; ws[w] = s; s += x; }
    }
    __syncthreads();
    int excl = inc - v + ws[wid] + boff[blockIdx.x];
    if (i < N_NODES) rowptr[i] = excl;
    if (i == N_NODES - 1) rowptr[N_NODES] = excl + v;
}

__global__ __launch_bounds__(256) void k_scatter(const int* __restrict__ ei,
                                                 const float* __restrict__ ea,
                                                 const int* __restrict__ rowptr,
                                                 int* __restrict__ fill,
                                                 uint2* __restrict__ csr)
{
    int e = blockIdx.x * 256 + threadIdx.x;
    int src = ei[e];
    int dst = ei[E_EDGES + e];
    int pos = rowptr[dst] + atomicAdd(&fill[dst], 1);
    csr[pos] = make_uint2((uint_t)src, __float_as_uint(ea[e]));
}

// ---- per-edge gate+message: packed VOP3P math, trans-hazard-safe ----
__device__ __forceinline__ void edge_acc(uint_t qw, uint_t uv, float ea,
                                         f32x2 we2, f32x2 be2, f32x2 kd2,
                                         f32x2 two2, f32x2 ln22, f32x2 one2,
                                         f32x2& acc)
{
    f32x2 q = cvtpk_q(qw);
    f32x2 v;
    v.x = __uint_as_float(uv << 16);
    v.y = __uint_as_float(uv & 0xffff0000u);
    f32x2 av; av.x = ea; av.y = ea;
    f32x2 ep = pk_fma(av, we2, be2);        // e' = (a*We+be)*log2e  (pre-scaled)
    f32x2 t  = pk_add(kd2, q);              // k' + q'
    f32x2 g  = pk_fma(two2, ep, t);         // gate arg (log2 domain)
    f32x2 ex; ex.x = EXP2F(-g.x); ex.y = EXP2F(-g.y);     // trans (compiler-visible)
    f32x2 d  = pk_add_tr(ex, one2);         // 1 + 2^-g   (s_nop-guarded)
    f32x2 sg; sg.x = __builtin_amdgcn_rcpf(d.x); sg.y = __builtin_amdgcn_rcpf(d.y);
    f32x2 m  = pk_fma(ln22, ep, v);         // v + e  (undo log2e scale)
    acc = pk_fma_tr(sg, m, acc);            // s_nop-guarded (rcp producer)
}

// ===== aggregation (one wave per dst node) + LayerNorm + GELU -> h (bf16) =====
// lane L handles features flo=32*(L>>4)+(L&15), fhi=flo+16.
__global__ __launch_bounds__(256) void k_agg_ln(const int* __restrict__ rowptr,
                                                const uint2* __restrict__ csr,
                                                const ushort_t* __restrict__ qf8,
                                                const uint_t* __restrict__ vb,
                                                const uint_t* __restrict__ ks,
                                                const float* __restrict__ We,
                                                const float* __restrict__ be,
                                                const float* __restrict__ gamma,
                                                const float* __restrict__ beta,
                                                ushort_t* __restrict__ hout)
{
    int tid = threadIdx.x;
    int lane = tid & 63;
    int node = blockIdx.x * 4 + (tid >> 6);
    int flo = ((lane >> 4) << 5) + (lane & 15);
    int fhi = flo + 16;
    uint_t qoff = (uint_t)lane << 1;   // byte offset within qf8 row
    uint_t voff = (uint_t)lane << 2;   // byte offset within vb row
    const char* qbase = (const char*)qf8;
    const char* vbase = (const char*)vb;

    f32x2 we2, be2, kd2, acc;
    we2.x = We[flo] * L2E; we2.y = We[fhi] * L2E;
    be2.x = be[flo] * L2E; be2.y = be[fhi] * L2E;
    uint_t klo = ks[(size_t)node * H + flo];
    uint_t khi = ks[(size_t)node * H + fhi];
    kd2.x = bf2f(klo & 0xffffu); kd2.y = bf2f(khi & 0xffffu);   // k' (·log2e)
    acc.x = bf2f(klo >> 16);     acc.y = bf2f(khi >> 16);       // h@Ws + b_gcn
    f32x2 two2 = (f32x2){2.f, 2.f};
    f32x2 ln22 = (f32x2){LN2, LN2};
    f32x2 one2 = (f32x2){1.f, 1.f};
    int p = rowptr[node];
    int pend = rowptr[node + 1];

#define GATH(QW, UV, A, C) { \
    A = __uint_as_float((C).y); \
    uint_t s_ = (C).x; \
    QW = *(const ushort_t*)(qbase + ((s_ << 7) + qoff)); \
    UV = *(const uint_t*)(vbase + ((s_ << 8) + voff)); }

    while (p + 8 <= pend) {
        uint2 c0 = csr[p],     c1 = csr[p + 1], c2 = csr[p + 2], c3 = csr[p + 3];
        uint2 c4 = csr[p + 4], c5 = csr[p + 5], c6 = csr[p + 6], c7 = csr[p + 7];
        uint_t w0, w1, w2, w3, w4, w5, w6, w7;
        uint_t u0, u1, u2, u3, u4, u5, u6, u7;
        float a0, a1, a2, a3, a4, a5, a6, a7;
        GATH(w0, u0, a0, c0); GATH(w1, u1, a1, c1); GATH(w2, u2, a2, c2); GATH(w3, u3, a3, c3);
        GATH(w4, u4, a4, c4); GATH(w5, u5, a5, c5); GATH(w6, u6, a6, c6); GATH(w7, u7, a7, c7);
        edge_acc(w0, u0, a0, we2, be2, kd2, two2, ln22, one2, acc);
        edge_acc(w1, u1, a1, we2, be2, kd2, two2, ln22, one2, acc);
        edge_acc(w2, u2, a2, we2, be2, kd2, two2, ln22, one2, acc);
        edge_acc(w3, u3, a3, we2, be2, kd2, two2, ln22, one2, acc);
        edge_acc(w4, u4, a4, we2, be2, kd2, two2, ln22, one2, acc);
        edge_acc(w5, u5, a5, we2, be2, kd2, two2, ln22, one2, acc);
        edge_acc(w6, u6, a6, we2, be2, kd2, two2, ln22, one2, acc);
        edge_acc(w7, u7, a7, we2, be2, kd2, two2, ln22, one2, acc);
        p += 8;
    }
    if (p + 4 <= pend) {
        uint2 c0 = csr[p], c1 = csr[p + 1], c2 = csr[p + 2], c3 = csr[p + 3];
        uint_t w0, w1, w2, w3;
        uint_t u0, u1, u2, u3;
        float a0, a1, a2, a3;
        GATH(w0, u0, a0, c0); GATH(w1, u1, a1, c1); GATH(w2, u2, a2, c2); GATH(w3, u3, a3, c3);
        edge_acc(w0, u0, a0, we2, be2, kd2, two2, ln22, one2, acc);
        edge_acc(w1, u1, a1, we2, be2, kd2, two2, ln22, one2, acc);
        edge_acc(w2, u2, a2, we2, be2, kd2, two2, ln22, one2, acc);
        edge_acc(w3, u3, a3, we2, be2, kd2, two2, ln22, one2, acc);
        p += 4;
    }
    for (; p < pend; ++p) {
        uint2 c = csr[p];
        uint_t qw, uv; float a;
        GATH(qw, uv, a, c);
        edge_acc(qw, uv, a, we2, be2, kd2, two2, ln22, one2, acc);
    }
#undef GATH

    float s  = acc.x + acc.y;
    float s2 = acc.x * acc.x + acc.y * acc.y;
    #pragma unroll
    for (int off = 32; off > 0; off >>= 1) {
        s  += __shfl_down(s, off);
        s2 += __shfl_down(s2, off);
    }
    s  = __shfl(s, 0);
    s2 = __shfl(s2, 0);
    float mu  = s * (1.f / H);
    float var = s2 * (1.f / H) - mu * mu;
    float rstd = rsqrtf(var + EPSF);
    float glo = gamma[flo], ghi = gamma[fhi];
    float blo = beta[flo],  bhi = beta[fhi];
    float y0 = (acc.x - mu) * rstd * glo + blo;
    float y1 = (acc.y - mu) * rstd * ghi + bhi;
    y0 = 0.5f * y0 * (1.f + erff(y0 * 0.70710678118f));
    y1 = 0.5f * y1 * (1.f + erff(y1 * 0.70710678118f));
    hout[(size_t)node * H + flo] = f2bf(y0);
    hout[(size_t)node * H + fhi] = f2bf(y1);
}

// ---------------- out_proj MFMA: out = h @ W_out (fp32 out) ----------------
__global__ __launch_bounds__(256) void k_out_mfma(const ushort_t* __restrict__ hb,
                                                  const ushort_t* __restrict__ Bout, // [64][128]
                                                  float* __restrict__ out)
{
    int gw = blockIdx.x * 4 + (threadIdx.x >> 6);
    if (gw >= 6250) return;
    int lane = threadIdx.x & 63;
    int rg = gw >> 1, cg = gw & 1;
    int r0 = rg * 16, c0 = cg * 32;
    const ushort_t* Ap = hb + (size_t)(r0 + (lane & 15)) * H + 8 * (lane >> 4);
    const ushort_t* Bp = Bout + (size_t)(c0 + (lane & 15)) * H + 8 * (lane >> 4);
    f32x4 acc[2];
    acc[0] = (f32x4){0.f, 0.f, 0.f, 0.f};
    acc[1] = (f32x4){0.f, 0.f, 0.f, 0.f};
    #pragma unroll
    for (int kk = 0; kk < 4; ++kk) {
        bf16x8 a = *(const bf16x8*)(Ap + kk * 32);
        bf16x8 b0 = *(const bf16x8*)(Bp + kk * 32);
        bf16x8 b1 = *(const bf16x8*)(Bp + 16 * H + kk * 32);
        acc[0] = __builtin_amdgcn_mfma_f32_16x16x32_bf16(a, b0, acc[0], 0, 0, 0);
        acc[1] = __builtin_amdgcn_mfma_f32_16x16x32_bf16(a, b1, acc[1], 0, 0, 0);
    }
    int rowb = r0 + ((lane >> 4) << 2);
    #pragma unroll
    for (int nf = 0; nf < 2; ++nf) {
        int col = c0 + nf * 16 + (lane & 15);
        #pragma unroll
        for (int j = 0; j < 4; ++j)
            out[(size_t)(rowb + j) * DOUT + col] = acc[nf][j];
    }
}

extern "C" void kernel_launch(void* const* d_in, const int* in_sizes, int n_in,
                              void* d_out, int out_size, void* d_ws, size_t ws_size,
                              hipStream_t stream) {
    const float* x         = (const float*)d_in[0];
    const float* edge_attr = (const float*)d_in[1];
    const float* W_in      = (const float*)d_in[2];
    const float* b_in      = (const float*)d_in[3];
    const float* Wk        = (const float*)d_in[4];
    const float* bk        = (const float*)d_in[5];
    const float* Wq        = (const float*)d_in[6];
    const float* bq        = (const float*)d_in[7];
    const float* Wv        = (const float*)d_in[8];
    const float* bv        = (const float*)d_in[9];
    const float* We        = (const float*)d_in[10];
    const float* be        = (const float*)d_in[11];
    const float* Ws        = (const float*)d_in[12];
    const float* b_gcn     = (const float*)d_in[13];
    const float* gamma     = (const float*)d_in[14];
    const float* beta      = (const float*)d_in[15];
    const float* W_out     = (const float*)d_in[16];
    const int*   edge_index= (const int*)d_in[17];
    float* out = (float*)d_out;

    char* wsb = (char*)d_ws;
    ushort_t* hb  = (ushort_t*)wsb;                  wsb += (size_t)NPAD * H * 2;
    ushort_t* qf8 = (ushort_t*)wsb;                  wsb += (size_t)NPAD * 64 * 2;
    uint_t*   vb  = (uint_t*)wsb;                    wsb += (size_t)NPAD * 64 * 4;
    uint_t*   ks  = (uint_t*)wsb;                    wsb += (size_t)NPAD * H * 4;
    ushort_t* xb  = (ushort_t*)wsb;                  wsb += (size_t)NPAD * DIN * 2;
    ushort_t* Bq  = (ushort_t*)wsb;                  wsb += 3 * 512 * 128 * 2;
    ushort_t* Bin = (ushort_t*)wsb;                  wsb += 128 * 256 * 2;
    ushort_t* Bout= (ushort_t*)wsb;                  wsb += 64 * 128 * 2;
    uint2* csr    = (uint2*)wsb;                     wsb += (size_t)E_EDGES * 8;
    int*   deg    = (int*)wsb;                       wsb += N_NODES * 4;
    int*   fill   = (int*)wsb;                       wsb += N_NODES * 4;
    int*   rowptr = (int*)wsb;                       wsb += (N_NODES + 1) * 4;
    int*   bsum   = (int*)wsb;                       wsb += NBLK * 4;
    int*   boff   = (int*)wsb;                       wsb += NBLK * 4;

    // CSR build (edge_index constant across layers)
    (void)hipMemsetAsync(deg, 0, 2 * N_NODES * sizeof(int), stream); // zeroes deg + fill
    k_hist<<<E_EDGES / 256, 256, 0, stream>>>(edge_index, deg);
    k_bsum<<<NBLK, 256, 0, stream>>>(deg, bsum);
    k_bscan<<<1, 256, 0, stream>>>(bsum, boff);
    k_rowptr<<<NBLK, 256, 0, stream>>>(deg, boff, rowptr);
    k_scatter<<<E_EDGES / 256, 256, 0, stream>>>(edge_index, edge_attr, rowptr, fill, csr);

    // conversions + weight packing
    k_convx<<<(N_NODES * DIN / 4 + 255) / 256, 256, 0, stream>>>(x, xb);
    k_pack<<<928, 256, 0, stream>>>(Wk, Wq, Wv, Ws, W_in, W_out, Bq, Bin, Bout);

    k_in_mfma<<<RT, 256, 0, stream>>>(xb, Bin, b_in, hb);
    for (int l = 0; l < 3; ++l) {
        k_qkvs_mfma<<<2 * RT, 256, 0, stream>>>(hb, Bq + (size_t)l * 512 * 128,
                                                bk + l * H, bq + l * H, bv + l * H, b_gcn + l * H,
                                                qf8, vb, ks);
        k_agg_ln<<<N_NODES / 4, 256, 0, stream>>>(rowptr, csr, qf8, vb, ks,
                                                  We + l * H, be + l * H,
                                                  gamma + l * H, beta + l * H, hb);
    }
    k_out_mfma<<<RT, 256, 0, stream>>>(hb, Bout, out);
}

// Round 14
// 417.820 us; speedup vs baseline: 1.0233x; 1.0233x over previous
//
#include <hip/hip_runtime.h>

#define N_NODES 50000
#define NPAD    50048   // padded row count (multiple of 64) so 32-row tiles need no guard
#define E_EDGES 800000
#define DIN 256
#define H 128
#define DOUT 64
#define EPSF 1e-5f
#define NBLK 196   // ceil(N_NODES/256)
#define RT   1563  // ceil(N_NODES/32) row tiles

typedef __bf16 bf16x8 __attribute__((ext_vector_type(8)));
typedef float  f32x4  __attribute__((ext_vector_type(4)));
typedef float  f32x2  __attribute__((ext_vector_type(2)));
typedef unsigned short ushort_t;
typedef unsigned int   uint_t;

#define L2E 1.4426950408889634f
#define LN2 0.6931471805599453f

#if __has_builtin(__builtin_amdgcn_exp2f)
#define EXP2F(x) __builtin_amdgcn_exp2f(x)
#else
#define EXP2F(x) __expf((x) * LN2)
#endif

__device__ inline float bf2f(uint_t u) {
    union { uint_t i; float f; } v; v.i = u << 16; return v.f;
}
__device__ inline ushort_t f2bf(float f) {
    uint_t u = __float_as_uint(f);
    uint_t r = (u + 0x7fffu + ((u >> 16) & 1u)) >> 16;
    return (ushort_t)r;
}

// ---- fp8 e4m3 helpers (hw path + software fallback) ----
#if __has_builtin(__builtin_amdgcn_cvt_f32_fp8)
#define FP8DEC(u, s) __builtin_amdgcn_cvt_f32_fp8((uint_t)(u), (s))
#else
__device__ inline float fp8_dec_sw(uint_t b) {
    uint_t s = (b & 0x80u) << 24;
    uint_t em = b & 0x7fu;
    if (em < 8u) return __uint_as_float(s);           // FTZ denormals
    uint_t ex = (em >> 3) + 120u;
    uint_t mn = (em & 7u) << 20;
    return __uint_as_float(s | (ex << 23) | mn);
}
#define FP8DEC(u, s) fp8_dec_sw(((uint_t)(u) >> (8 * (s))) & 0xffu)
#endif

// paired fp8 decode: 2 fp8 (low 16 bits) -> 2 floats
#if __has_builtin(__builtin_amdgcn_cvt_pk_f32_fp8)
__device__ __forceinline__ f32x2 cvtpk_q(uint_t u) {
    auto r = __builtin_amdgcn_cvt_pk_f32_fp8(u, false);
    f32x2 o; o.x = r[0]; o.y = r[1]; return o;
}
#else
__device__ __forceinline__ f32x2 cvtpk_q(uint_t u) {
    f32x2 r; r.x = FP8DEC(u, 0); r.y = FP8DEC(u, 1); return r;
}
#endif

#if __has_builtin(__builtin_amdgcn_cvt_pk_fp8_f32)
__device__ inline uint_t fp8_pk(float a, float b) {
    return (uint_t)__builtin_amdgcn_cvt_pk_fp8_f32(a, b, 0, false) & 0xffffu;
}
#else
__device__ inline uint_t fp8_enc_sw(float f) {
    uint_t u = __float_as_uint(f);
    uint_t s = (u >> 24) & 0x80u;
    uint_t a = u & 0x7fffffffu;
    if (a < 0x3c800000u) return s;           // |f| < 2^-6 -> 0
    if (a > 0x43e00000u) a = 0x43e00000u;    // clamp to 448
    uint_t r = a + 0x7ffffu + ((a >> 20) & 1u);
    uint_t ex = (r >> 23) - 120u;
    uint_t mn = (r >> 20) & 7u;
    return s | (ex << 3) | mn;
}
__device__ inline uint_t fp8_pk(float a, float b) {
    return fp8_enc_sw(a) | (fp8_enc_sw(b) << 8);
}
#endif

// ---------------- x -> bf16 ----------------
__global__ __launch_bounds__(256) void k_convx(const float* __restrict__ x, ushort_t* __restrict__ xb)
{
    int i = blockIdx.x * 256 + threadIdx.x;
    float4 v = ((const float4*)x)[i];
    ushort4 o;
    o.x = f2bf(v.x); o.y = f2bf(v.y); o.z = f2bf(v.z); o.w = f2bf(v.w);
    ((ushort4*)xb)[i] = o;
}

// ----------- merged weight packing (B^T layouts) -----------
__global__ __launch_bounds__(256) void k_pack(const float* __restrict__ Wk, const float* __restrict__ Wq,
                                              const float* __restrict__ Wv, const float* __restrict__ Ws,
                                              const float* __restrict__ W_in, const float* __restrict__ W_out,
                                              ushort_t* __restrict__ Bq, ushort_t* __restrict__ Bin,
                                              ushort_t* __restrict__ Bout)
{
    int t = blockIdx.x * 256 + threadIdx.x;
    if (t < 196608) {
        int l = t >> 16;
        int r = t & 65535;
        int c = r >> 7;
        int k = r & 127;
        int m = c >> 7;
        int cm = c & 127;
        const float* W = (m == 0) ? Wk : (m == 1) ? Wq : (m == 2) ? Wv : Ws;
        Bq[t] = f2bf(W[(size_t)l * H * H + k * H + cm]);
    } else if (t < 229376) {
        int t2 = t - 196608;
        int c = t2 >> 8;
        int k = t2 & 255;
        Bin[t2] = f2bf(W_in[k * H + c]);
    } else {
        int t3 = t - 229376;
        int c = t3 >> 7;
        int k = t3 & 127;
        Bout[t3] = f2bf(W_out[k * DOUT + c]);
    }
}

// ---------------- in_proj MFMA: h = bf16(x @ W_in + b_in) ----------------
__global__ __launch_bounds__(256) void k_in_mfma(const ushort_t* __restrict__ xb,
                                                 const ushort_t* __restrict__ Bin,
                                                 const float* __restrict__ b_in,
                                                 ushort_t* __restrict__ hb)
{
    int gw = blockIdx.x * 4 + (threadIdx.x >> 6);
    int lane = threadIdx.x & 63;
    int rt = gw >> 2, c32 = (gw & 3) * 32;
    int r0 = rt * 32;
    const ushort_t* Ap = xb + (size_t)(r0 + (lane & 15)) * DIN + 8 * (lane >> 4);
    const ushort_t* Bp = Bin + (size_t)(c32 + (lane & 15)) * DIN + 8 * (lane >> 4);
    f32x4 acc[2][2]; // [rb][nf]
    #pragma unroll
    for (int rb = 0; rb < 2; ++rb)
        #pragma unroll
        for (int nf = 0; nf < 2; ++nf) acc[rb][nf] = (f32x4){0.f, 0.f, 0.f, 0.f};
    #pragma unroll
    for (int ks = 0; ks < 8; ++ks) {
        bf16x8 a0 = *(const bf16x8*)(Ap + ks * 32);
        bf16x8 a1 = *(const bf16x8*)(Ap + 16 * DIN + ks * 32);
        bf16x8 b0 = *(const bf16x8*)(Bp + ks * 32);
        bf16x8 b1 = *(const bf16x8*)(Bp + 16 * DIN + ks * 32);
        acc[0][0] = __builtin_amdgcn_mfma_f32_16x16x32_bf16(a0, b0, acc[0][0], 0, 0, 0);
        acc[1][0] = __builtin_amdgcn_mfma_f32_16x16x32_bf16(a1, b0, acc[1][0], 0, 0, 0);
        acc[0][1] = __builtin_amdgcn_mfma_f32_16x16x32_bf16(a0, b1, acc[0][1], 0, 0, 0);
        acc[1][1] = __builtin_amdgcn_mfma_f32_16x16x32_bf16(a1, b1, acc[1][1], 0, 0, 0);
    }
    int rowoff = (lane >> 4) << 2;
    #pragma unroll
    for (int nf = 0; nf < 2; ++nf) {
        int col = c32 + nf * 16 + (lane & 15);
        float bb = b_in[col];
        #pragma unroll
        for (int rb = 0; rb < 2; ++rb)
            #pragma unroll
            for (int j = 0; j < 4; ++j)
                hb[(size_t)(r0 + rb * 16 + rowoff + j) * H + col] = f2bf(acc[rb][nf][j] + bb);
    }
}

// ------ qkvs MFMA ------
// pair 0 -> qf8 (fp8 q', 2/ushort) + vb (2 bf16 v / uint), entry e={f, f+16}
// pair 1 -> ks (uint: hi=agg bf16, lo=k' bf16), standard col index
__global__ __launch_bounds__(256) void k_qkvs_mfma(const ushort_t* __restrict__ hb,
                                                   const ushort_t* __restrict__ Bq, // [512][128]
                                                   const float* __restrict__ bk, const float* __restrict__ bq,
                                                   const float* __restrict__ bv, const float* __restrict__ bs,
                                                   ushort_t* __restrict__ qf8, uint_t* __restrict__ vb,
                                                   uint_t* __restrict__ ks)
{
    int gw = blockIdx.x * 4 + (threadIdx.x >> 6);
    int lane = threadIdx.x & 63;
    int rt = gw >> 3, cfg = gw & 7;
    int pair = cfg >> 2, c32 = (cfg & 3) * 32;
    int r0 = rt * 32;
    const ushort_t* Ap = hb + (size_t)(r0 + (lane & 15)) * H + 8 * (lane >> 4);
    int cb0 = pair ? 0   : 128;   // k : q
    int cb1 = pair ? 384 : 256;   // s : v
    const ushort_t* Bp0 = Bq + (size_t)(cb0 + c32 + (lane & 15)) * H + 8 * (lane >> 4);
    const ushort_t* Bp1 = Bq + (size_t)(cb1 + c32 + (lane & 15)) * H + 8 * (lane >> 4);
    f32x4 acc[2][2][2]; // [rb][mat][nf]
    #pragma unroll
    for (int rb = 0; rb < 2; ++rb)
        #pragma unroll
        for (int m = 0; m < 2; ++m)
            #pragma unroll
            for (int nf = 0; nf < 2; ++nf) acc[rb][m][nf] = (f32x4){0.f, 0.f, 0.f, 0.f};
    #pragma unroll
    for (int kk = 0; kk < 4; ++kk) {
        bf16x8 a0 = *(const bf16x8*)(Ap + kk * 32);
        bf16x8 a1 = *(const bf16x8*)(Ap + 16 * H + kk * 32);
        #pragma unroll
        for (int nf = 0; nf < 2; ++nf) {
            bf16x8 b0 = *(const bf16x8*)(Bp0 + nf * 16 * H + kk * 32);
            bf16x8 b1 = *(const bf16x8*)(Bp1 + nf * 16 * H + kk * 32);
            acc[0][0][nf] = __builtin_amdgcn_mfma_f32_16x16x32_bf16(a0, b0, acc[0][0][nf], 0, 0, 0);
            acc[1][0][nf] = __builtin_amdgcn_mfma_f32_16x16x32_bf16(a1, b0, acc[1][0][nf], 0, 0, 0);
            acc[0][1][nf] = __builtin_amdgcn_mfma_f32_16x16x32_bf16(a0, b1, acc[0][1][nf], 0, 0, 0);
            acc[1][1][nf] = __builtin_amdgcn_mfma_f32_16x16x32_bf16(a1, b1, acc[1][1][nf], 0, 0, 0);
        }
    }
    int rowoff = (lane >> 4) << 2;
    int l15 = lane & 15;
    if (pair == 0) {
        int col_lo = c32 + l15, col_hi = col_lo + 16;
        int e = (c32 >> 1) + l15;
        float bql = bq[col_lo], bqh = bq[col_hi];
        float bvl = bv[col_lo], bvh = bv[col_hi];
        #pragma unroll
        for (int rb = 0; rb < 2; ++rb)
            #pragma unroll
            for (int j = 0; j < 4; ++j) {
                size_t row = r0 + rb * 16 + rowoff + j;
                float ql = (acc[rb][0][0][j] + bql) * L2E;
                float qh = (acc[rb][0][1][j] + bqh) * L2E;
                qf8[row * 64 + e] = (ushort_t)fp8_pk(ql, qh);
                uint_t vl = f2bf(acc[rb][1][0][j] + bvl);
                uint_t vh = f2bf(acc[rb][1][1][j] + bvh);
                vb[row * 64 + e] = (vh << 16) | vl;
            }
    } else {
        #pragma unroll
        for (int nf = 0; nf < 2; ++nf) {
            int col = c32 + nf * 16 + l15;
            float bbk = bk[col], bbs = bs[col];
            #pragma unroll
            for (int rb = 0; rb < 2; ++rb)
                #pragma unroll
                for (int j = 0; j < 4; ++j) {
                    size_t row = r0 + rb * 16 + rowoff + j;
                    uint_t kkv = f2bf((acc[rb][0][nf][j] + bbk) * L2E);
                    uint_t ssv = f2bf(acc[rb][1][nf][j] + bbs);
                    ks[row * H + col] = (ssv << 16) | kkv;
                }
        }
    }
}

// ================= CSR build =================
__global__ __launch_bounds__(256) void k_hist(const int* __restrict__ ei, int* __restrict__ deg)
{
    int e = blockIdx.x * 256 + threadIdx.x;
    int dst = ei[E_EDGES + e];
    atomicAdd(&deg[dst], 1);
}

__global__ __launch_bounds__(256) void k_bsum(const int* __restrict__ deg, int* __restrict__ bsum)
{
    __shared__ int ws[4];
    int t = threadIdx.x;
    int i = blockIdx.x * 256 + t;
    int v = (i < N_NODES) ? deg[i] : 0;
    #pragma unroll
    for (int off = 32; off > 0; off >>= 1) v += __shfl_down(v, off);
    if ((t & 63) == 0) ws[t >> 6] = v;
    __syncthreads();
    if (t == 0) bsum[blockIdx.x] = ws[0] + ws[1] + ws[2] + ws[3];
}

__global__ __launch_bounds__(256) void k_bscan(const int* __restrict__ bsum, int* __restrict__ boff)
{
    __shared__ int ws[4];
    int t = threadIdx.x;
    int v = (t < NBLK) ? bsum[t] : 0;
    int lane = t & 63, wid = t >> 6;
    int inc = v;
    #pragma unroll
    for (int off = 1; off < 64; off <<= 1) {
        int u = __shfl_up(inc, off);
        if (lane >= off) inc += u;
    }
    if (lane == 63) ws[wid] = inc;
    __syncthreads();
    if (t == 0) {
        int s = 0;
        #pragma unroll
        for (int w = 0; w < 4; ++w) { int x = ws[w]; ws[w] = s; s += x; }
    }
    __syncthreads();
    if (t < NBLK) boff[t] = inc - v + ws[wid];
}

__global__ __launch_bounds__(256) void k_rowptr(const int* __restrict__ deg,
                                                const int* __restrict__ boff,
                                                int* __restrict__ rowptr)
{
    __shared__ int ws[4];
    int t = threadIdx.x;
    int i = blockIdx.x * 256 + t;
    int v = (i < N_NODES) ? deg[i] : 0;
    int lane = t & 63, wid = t >> 6;
    int inc = v;
    #pragma unroll
    for (int off = 1; off < 64; off <<= 1) {
        int u = __shfl_up(inc, off);
        if (lane >= off) inc += u;
    }
    if (lane == 63) ws[wid] = inc;
    __syncthreads();
    if (t == 0) {
        int s = 0;
        #pragma unroll
        for (int w = 0; w < 4; ++w) { int x = ws[w]; ws[w] = s; s += x; }
    }
    __syncthreads();
    int excl = inc - v + ws[wid] + boff[blockIdx.x];
    if (i < N_NODES) rowptr[i] = excl;
    if (i == N_NODES - 1) rowptr[N_NODES] = excl + v;
}

__global__ __launch_bounds__(256) void k_scatter(const int* __restrict__ ei,
                                                 const float* __restrict__ ea,
                                                 const int* __restrict__ rowptr,
                                                 int* __restrict__ fill,
                                                 uint2* __restrict__ csr)
{
    int e = blockIdx.x * 256 + threadIdx.x;
    int src = ei[e];
    int dst = ei[E_EDGES + e];
    int pos = rowptr[dst] + atomicAdd(&fill[dst], 1);
    csr[pos] = make_uint2((uint_t)src, __float_as_uint(ea[e]));
}

// ---- per-edge gate+message (round-11 builtin math: best known good) ----
__device__ __forceinline__ void edge_acc(uint_t qw, uint_t uv, float ea,
                                         f32x2 we2, f32x2 be2, f32x2 kd2, f32x2& acc)
{
    f32x2 q = cvtpk_q(qw);
    f32x2 v;
    v.x = __uint_as_float(uv << 16);
    v.y = __uint_as_float(uv & 0xffff0000u);
    f32x2 av; av.x = ea; av.y = ea;
    f32x2 ep = __builtin_elementwise_fma(av, we2, be2);       // e' (·log2e)
    f32x2 g  = __builtin_elementwise_fma((f32x2){2.f, 2.f}, ep, kd2 + q);
    f32x2 ex; ex.x = EXP2F(-g.x); ex.y = EXP2F(-g.y);
    f32x2 d = ex + (f32x2){1.f, 1.f};
    f32x2 sg; sg.x = __builtin_amdgcn_rcpf(d.x); sg.y = __builtin_amdgcn_rcpf(d.y);
    f32x2 m = __builtin_elementwise_fma((f32x2){LN2, LN2}, ep, v); // v + e
    acc = __builtin_elementwise_fma(sg, m, acc);
}

// ===== aggregation (one wave per dst node) + LayerNorm + GELU -> h (bf16) =====
// Wave-uniform scalarization: node/rowptr/csr through SGPRs (s_load), gather
// rows via uniform base + lane voffset (saddr-form loads, zero VALU addressing).
__global__ __launch_bounds__(256) void k_agg_ln(const int* __restrict__ rowptr,
                                                const uint2* __restrict__ csr,
                                                const ushort_t* __restrict__ qf8,
                                                const uint_t* __restrict__ vb,
                                                const uint_t* __restrict__ ks,
                                                const float* __restrict__ We,
                                                const float* __restrict__ be,
                                                const float* __restrict__ gamma,
                                                const float* __restrict__ beta,
                                                ushort_t* __restrict__ hout)
{
    int tid = threadIdx.x;
    int lane = tid & 63;
    int node = __builtin_amdgcn_readfirstlane(blockIdx.x * 4 + (tid >> 6));
    int flo = ((lane >> 4) << 5) + (lane & 15);
    int fhi = flo + 16;

    f32x2 we2, be2, kd2, acc;
    we2.x = We[flo] * L2E; we2.y = We[fhi] * L2E;
    be2.x = be[flo] * L2E; be2.y = be[fhi] * L2E;
    uint_t klo = ks[(size_t)node * H + flo];
    uint_t khi = ks[(size_t)node * H + fhi];
    kd2.x = bf2f(klo & 0xffffu); kd2.y = bf2f(khi & 0xffffu);   // k' (·log2e)
    acc.x = bf2f(klo >> 16);     acc.y = bf2f(khi >> 16);       // h@Ws + b_gcn
    int p = rowptr[node];        // uniform -> s_load
    int pend = rowptr[node + 1];

// c is wave-uniform (s_load); gather base is SALU, load is saddr + lane voffset
#define GATH(QW, UV, A, C) { \
    A = __uint_as_float((C).y); \
    const ushort_t* qrow_ = qf8 + ((size_t)(C).x << 6); \
    const uint_t*   vrow_ = vb  + ((size_t)(C).x << 6); \
    QW = qrow_[lane]; \
    UV = vrow_[lane]; }

    while (p + 8 <= pend) {
        uint2 c0 = csr[p],     c1 = csr[p + 1], c2 = csr[p + 2], c3 = csr[p + 3];
        uint2 c4 = csr[p + 4], c5 = csr[p + 5], c6 = csr[p + 6], c7 = csr[p + 7];
        uint_t w0, w1, w2, w3, w4, w5, w6, w7;
        uint_t u0, u1, u2, u3, u4, u5, u6, u7;
        float a0, a1, a2, a3, a4, a5, a6, a7;
        GATH(w0, u0, a0, c0); GATH(w1, u1, a1, c1); GATH(w2, u2, a2, c2); GATH(w3, u3, a3, c3);
        GATH(w4, u4, a4, c4); GATH(w5, u5, a5, c5); GATH(w6, u6, a6, c6); GATH(w7, u7, a7, c7);
        edge_acc(w0, u0, a0, we2, be2, kd2, acc);
        edge_acc(w1, u1, a1, we2, be2, kd2, acc);
        edge_acc(w2, u2, a2, we2, be2, kd2, acc);
        edge_acc(w3, u3, a3, we2, be2, kd2, acc);
        edge_acc(w4, u4, a4, we2, be2, kd2, acc);
        edge_acc(w5, u5, a5, we2, be2, kd2, acc);
        edge_acc(w6, u6, a6, we2, be2, kd2, acc);
        edge_acc(w7, u7, a7, we2, be2, kd2, acc);
        p += 8;
    }
    if (p + 4 <= pend) {
        uint2 c0 = csr[p], c1 = csr[p + 1], c2 = csr[p + 2], c3 = csr[p + 3];
        uint_t w0, w1, w2, w3;
        uint_t u0, u1, u2, u3;
        float a0, a1, a2, a3;
        GATH(w0, u0, a0, c0); GATH(w1, u1, a1, c1); GATH(w2, u2, a2, c2); GATH(w3, u3, a3, c3);
        edge_acc(w0, u0, a0, we2, be2, kd2, acc);
        edge_acc(w1, u1, a1, we2, be2, kd2, acc);
        edge_acc(w2, u2, a2, we2, be2, kd2, acc);
        edge_acc(w3, u3, a3, we2, be2, kd2, acc);
        p += 4;
    }
    for (; p < pend; ++p) {
        uint2 c = csr[p];
        uint_t qw, uv; float a;
        GATH(qw, uv, a, c);
        edge_acc(qw, uv, a, we2, be2, kd2, acc);
    }
#undef GATH

    float s  = acc.x + acc.y;
    float s2 = acc.x * acc.x + acc.y * acc.y;
    #pragma unroll
    for (int off = 32; off > 0; off >>= 1) {
        s  += __shfl_down(s, off);
        s2 += __shfl_down(s2, off);
    }
    s  = __shfl(s, 0);
    s2 = __shfl(s2, 0);
    float mu  = s * (1.f / H);
    float var = s2 * (1.f / H) - mu * mu;
    float rstd = rsqrtf(var + EPSF);
    float glo = gamma[flo], ghi = gamma[fhi];
    float blo = beta[flo],  bhi = beta[fhi];
    float y0 = (acc.x - mu) * rstd * glo + blo;
    float y1 = (acc.y - mu) * rstd * ghi + bhi;
    y0 = 0.5f * y0 * (1.f + erff(y0 * 0.70710678118f));
    y1 = 0.5f * y1 * (1.f + erff(y1 * 0.70710678118f));
    hout[(size_t)node * H + flo] = f2bf(y0);
    hout[(size_t)node * H + fhi] = f2bf(y1);
}

// ---------------- out_proj MFMA: out = h @ W_out (fp32 out) ----------------
__global__ __launch_bounds__(256) void k_out_mfma(const ushort_t* __restrict__ hb,
                                                  const ushort_t* __restrict__ Bout, // [64][128]
                                                  float* __restrict__ out)
{
    int gw = blockIdx.x * 4 + (threadIdx.x >> 6);
    if (gw >= 6250) return;
    int lane = threadIdx.x & 63;
    int rg = gw >> 1, cg = gw & 1;
    int r0 = rg * 16, c0 = cg * 32;
    const ushort_t* Ap = hb + (size_t)(r0 + (lane & 15)) * H + 8 * (lane >> 4);
    const ushort_t* Bp = Bout + (size_t)(c0 + (lane & 15)) * H + 8 * (lane >> 4);
    f32x4 acc[2];
    acc[0] = (f32x4){0.f, 0.f, 0.f, 0.f};
    acc[1] = (f32x4){0.f, 0.f, 0.f, 0.f};
    #pragma unroll
    for (int kk = 0; kk < 4; ++kk) {
        bf16x8 a = *(const bf16x8*)(Ap + kk * 32);
        bf16x8 b0 = *(const bf16x8*)(Bp + kk * 32);
        bf16x8 b1 = *(const bf16x8*)(Bp + 16 * H + kk * 32);
        acc[0] = __builtin_amdgcn_mfma_f32_16x16x32_bf16(a, b0, acc[0], 0, 0, 0);
        acc[1] = __builtin_amdgcn_mfma_f32_16x16x32_bf16(a, b1, acc[1], 0, 0, 0);
    }
    int rowb = r0 + ((lane >> 4) << 2);
    #pragma unroll
    for (int nf = 0; nf < 2; ++nf) {
        int col = c0 + nf * 16 + (lane & 15);
        #pragma unroll
        for (int j = 0; j < 4; ++j)
            out[(size_t)(rowb + j) * DOUT + col] = acc[nf][j];
    }
}

extern "C" void kernel_launch(void* const* d_in, const int* in_sizes, int n_in,
                              void* d_out, int out_size, void* d_ws, size_t ws_size,
                              hipStream_t stream) {
    const float* x         = (const float*)d_in[0];
    const float* edge_attr = (const float*)d_in[1];
    const float* W_in      = (const float*)d_in[2];
    const float* b_in      = (const float*)d_in[3];
    const float* Wk        = (const float*)d_in[4];
    const float* bk        = (const float*)d_in[5];
    const float* Wq        = (const float*)d_in[6];
    const float* bq        = (const float*)d_in[7];
    const float* Wv        = (const float*)d_in[8];
    const float* bv        = (const float*)d_in[9];
    const float* We        = (const float*)d_in[10];
    const float* be        = (const float*)d_in[11];
    const float* Ws        = (const float*)d_in[12];
    const float* b_gcn     = (const float*)d_in[13];
    const float* gamma     = (const float*)d_in[14];
    const float* beta      = (const float*)d_in[15];
    const float* W_out     = (const float*)d_in[16];
    const int*   edge_index= (const int*)d_in[17];
    float* out = (float*)d_out;

    char* wsb = (char*)d_ws;
    ushort_t* hb  = (ushort_t*)wsb;                  wsb += (size_t)NPAD * H * 2;
    ushort_t* qf8 = (ushort_t*)wsb;                  wsb += (size_t)NPAD * 64 * 2;
    uint_t*   vb  = (uint_t*)wsb;                    wsb += (size_t)NPAD * 64 * 4;
    uint_t*   ks  = (uint_t*)wsb;                    wsb += (size_t)NPAD * H * 4;
    ushort_t* xb  = (ushort_t*)wsb;                  wsb += (size_t)NPAD * DIN * 2;
    ushort_t* Bq  = (ushort_t*)wsb;                  wsb += 3 * 512 * 128 * 2;
    ushort_t* Bin = (ushort_t*)wsb;                  wsb += 128 * 256 * 2;
    ushort_t* Bout= (ushort_t*)wsb;                  wsb += 64 * 128 * 2;
    uint2* csr    = (uint2*)wsb;                     wsb += (size_t)E_EDGES * 8;
    int*   deg    = (int*)wsb;                       wsb += N_NODES * 4;
    int*   fill   = (int*)wsb;                       wsb += N_NODES * 4;
    int*   rowptr = (int*)wsb;                       wsb += (N_NODES + 1) * 4;
    int*   bsum   = (int*)wsb;                       wsb += NBLK * 4;
    int*   boff   = (int*)wsb;                       wsb += NBLK * 4;

    // CSR build (edge_index constant across layers)
    (void)hipMemsetAsync(deg, 0, 2 * N_NODES * sizeof(int), stream); // zeroes deg + fill
    k_hist<<<E_EDGES / 256, 256, 0, stream>>>(edge_index, deg);
    k_bsum<<<NBLK, 256, 0, stream>>>(deg, bsum);
    k_bscan<<<1, 256, 0, stream>>>(bsum, boff);
    k_rowptr<<<NBLK, 256, 0, stream>>>(deg, boff, rowptr);
    k_scatter<<<E_EDGES / 256, 256, 0, stream>>>(edge_index, edge_attr, rowptr, fill, csr);

    // conversions + weight packing
    k_convx<<<(N_NODES * DIN / 4 + 255) / 256, 256, 0, stream>>>(x, xb);
    k_pack<<<928, 256, 0, stream>>>(Wk, Wq, Wv, Ws, W_in, W_out, Bq, Bin, Bout);

    k_in_mfma<<<RT, 256, 0, stream>>>(xb, Bin, b_in, hb);
    for (int l = 0; l < 3; ++l) {
        k_qkvs_mfma<<<2 * RT, 256, 0, stream>>>(hb, Bq + (size_t)l * 512 * 128,
                                                bk + l * H, bq + l * H, bv + l * H, b_gcn + l * H,
                                                qf8, vb, ks);
        k_agg_ln<<<N_NODES / 4, 256, 0, stream>>>(rowptr, csr, qf8, vb, ks,
                                                  We + l * H, be + l * H,
                                                  gamma + l * H, beta + l * H, hb);
    }
    k_out_mfma<<<RT, 256, 0, stream>>>(hb, Bout, out);
}

// Round 15
// 400.877 us; speedup vs baseline: 1.0666x; 1.0423x over previous
//
#include <hip/hip_runtime.h>

#define N_NODES 50000
#define NPAD    50048   // padded row count (multiple of 64) so 32-row tiles need no guard
#define E_EDGES 800000
#define DIN 256
#define H 128
#define DOUT 64
#define EPSF 1e-5f
#define NBLK 196   // ceil(N_NODES/256)
#define RT   1563  // ceil(N_NODES/32) row tiles
#define CVB  12500 // convx blocks
#define PKB  928   // pack blocks
#define HSB  3125  // hist blocks
#define SCB  782   // scatter blocks (4 edges/thread, 1024 edges/block)

typedef __bf16 bf16x8 __attribute__((ext_vector_type(8)));
typedef float  f32x4  __attribute__((ext_vector_type(4)));
typedef float  f32x2  __attribute__((ext_vector_type(2)));
typedef unsigned short ushort_t;
typedef unsigned int   uint_t;

#define L2E 1.4426950408889634f
#define LN2 0.6931471805599453f

#if __has_builtin(__builtin_amdgcn_exp2f)
#define EXP2F(x) __builtin_amdgcn_exp2f(x)
#else
#define EXP2F(x) __expf((x) * LN2)
#endif

__device__ inline float bf2f(uint_t u) {
    union { uint_t i; float f; } v; v.i = u << 16; return v.f;
}
__device__ inline ushort_t f2bf(float f) {
    uint_t u = __float_as_uint(f);
    uint_t r = (u + 0x7fffu + ((u >> 16) & 1u)) >> 16;
    return (ushort_t)r;
}

// ---- fp8 e4m3 helpers (hw path + software fallback) ----
#if __has_builtin(__builtin_amdgcn_cvt_f32_fp8)
#define FP8DEC(u, s) __builtin_amdgcn_cvt_f32_fp8((uint_t)(u), (s))
#else
__device__ inline float fp8_dec_sw(uint_t b) {
    uint_t s = (b & 0x80u) << 24;
    uint_t em = b & 0x7fu;
    if (em < 8u) return __uint_as_float(s);           // FTZ denormals
    uint_t ex = (em >> 3) + 120u;
    uint_t mn = (em & 7u) << 20;
    return __uint_as_float(s | (ex << 23) | mn);
}
#define FP8DEC(u, s) fp8_dec_sw(((uint_t)(u) >> (8 * (s))) & 0xffu)
#endif

// paired fp8 decode: 2 fp8 (low 16 bits) -> 2 floats
#if __has_builtin(__builtin_amdgcn_cvt_pk_f32_fp8)
__device__ __forceinline__ f32x2 cvtpk_q(uint_t u) {
    auto r = __builtin_amdgcn_cvt_pk_f32_fp8(u, false);
    f32x2 o; o.x = r[0]; o.y = r[1]; return o;
}
#else
__device__ __forceinline__ f32x2 cvtpk_q(uint_t u) {
    f32x2 r; r.x = FP8DEC(u, 0); r.y = FP8DEC(u, 1); return r;
}
#endif

#if __has_builtin(__builtin_amdgcn_cvt_pk_fp8_f32)
__device__ inline uint_t fp8_pk(float a, float b) {
    return (uint_t)__builtin_amdgcn_cvt_pk_fp8_f32(a, b, 0, false) & 0xffffu;
}
#else
__device__ inline uint_t fp8_enc_sw(float f) {
    uint_t u = __float_as_uint(f);
    uint_t s = (u >> 24) & 0x80u;
    uint_t a = u & 0x7fffffffu;
    if (a < 0x3c800000u) return s;           // |f| < 2^-6 -> 0
    if (a > 0x43e00000u) a = 0x43e00000u;    // clamp to 448
    uint_t r = a + 0x7ffffu + ((a >> 20) & 1u);
    uint_t ex = (r >> 23) - 120u;
    uint_t mn = (r >> 20) & 7u;
    return s | (ex << 3) | mn;
}
__device__ inline uint_t fp8_pk(float a, float b) {
    return fp8_enc_sw(a) | (fp8_enc_sw(b) << 8);
}
#endif

// ======= fused pre-pass: convx ∥ weight-pack ∥ edge histogram =======
__global__ __launch_bounds__(256) void k_pre(const float* __restrict__ x, ushort_t* __restrict__ xb,
                                             const float* __restrict__ Wk, const float* __restrict__ Wq,
                                             const float* __restrict__ Wv, const float* __restrict__ Ws,
                                             const float* __restrict__ W_in, const float* __restrict__ W_out,
                                             ushort_t* __restrict__ Bq, ushort_t* __restrict__ Bin,
                                             ushort_t* __restrict__ Bout,
                                             const int* __restrict__ ei, int* __restrict__ deg)
{
    int b = blockIdx.x;
    int tid = threadIdx.x;
    if (b < CVB) {
        int i = b * 256 + tid;
        float4 v = ((const float4*)x)[i];
        ushort4 o;
        o.x = f2bf(v.x); o.y = f2bf(v.y); o.z = f2bf(v.z); o.w = f2bf(v.w);
        ((ushort4*)xb)[i] = o;
    } else if (b < CVB + PKB) {
        int t = (b - CVB) * 256 + tid;
        if (t < 196608) {
            int l = t >> 16;
            int r = t & 65535;
            int c = r >> 7;
            int k = r & 127;
            int m = c >> 7;
            int cm = c & 127;
            const float* W = (m == 0) ? Wk : (m == 1) ? Wq : (m == 2) ? Wv : Ws;
            Bq[t] = f2bf(W[(size_t)l * H * H + k * H + cm]);
        } else if (t < 229376) {
            int t2 = t - 196608;
            int c = t2 >> 8;
            int k = t2 & 255;
            Bin[t2] = f2bf(W_in[k * H + c]);
        } else {
            int t3 = t - 229376;
            int c = t3 >> 7;
            int k = t3 & 127;
            Bout[t3] = f2bf(W_out[k * DOUT + c]);
        }
    } else {
        int e = (b - CVB - PKB) * 256 + tid;
        int dst = ei[E_EDGES + e];
        atomicAdd(&deg[dst], 1);
    }
}

// ======= fused mid-pass: in_proj MFMA ∥ CSR scatter =======
__global__ __launch_bounds__(256) void k_mid(const ushort_t* __restrict__ xb,
                                             const ushort_t* __restrict__ Bin,
                                             const float* __restrict__ b_in,
                                             ushort_t* __restrict__ hb,
                                             const int* __restrict__ ei,
                                             const float* __restrict__ ea,
                                             const int* __restrict__ rowptr,
                                             int* __restrict__ fill,
                                             uint2* __restrict__ csr)
{
    int blk = blockIdx.x;
    int tid = threadIdx.x;
    if (blk < RT) {
        // ---- in_proj MFMA: 32 rows x 32 cols per wave, K=256 ----
        int gw = blk * 4 + (tid >> 6);
        int lane = tid & 63;
        int rt = gw >> 2, c32 = (gw & 3) * 32;
        int r0 = rt * 32;
        const ushort_t* Ap = xb + (size_t)(r0 + (lane & 15)) * DIN + 8 * (lane >> 4);
        const ushort_t* Bp = Bin + (size_t)(c32 + (lane & 15)) * DIN + 8 * (lane >> 4);
        f32x4 acc[2][2]; // [rb][nf]
        #pragma unroll
        for (int rb = 0; rb < 2; ++rb)
            #pragma unroll
            for (int nf = 0; nf < 2; ++nf) acc[rb][nf] = (f32x4){0.f, 0.f, 0.f, 0.f};
        #pragma unroll
        for (int ks = 0; ks < 8; ++ks) {
            bf16x8 a0 = *(const bf16x8*)(Ap + ks * 32);
            bf16x8 a1 = *(const bf16x8*)(Ap + 16 * DIN + ks * 32);
            bf16x8 b0 = *(const bf16x8*)(Bp + ks * 32);
            bf16x8 b1 = *(const bf16x8*)(Bp + 16 * DIN + ks * 32);
            acc[0][0] = __builtin_amdgcn_mfma_f32_16x16x32_bf16(a0, b0, acc[0][0], 0, 0, 0);
            acc[1][0] = __builtin_amdgcn_mfma_f32_16x16x32_bf16(a1, b0, acc[1][0], 0, 0, 0);
            acc[0][1] = __builtin_amdgcn_mfma_f32_16x16x32_bf16(a0, b1, acc[0][1], 0, 0, 0);
            acc[1][1] = __builtin_amdgcn_mfma_f32_16x16x32_bf16(a1, b1, acc[1][1], 0, 0, 0);
        }
        int rowoff = (lane >> 4) << 2;
        #pragma unroll
        for (int nf = 0; nf < 2; ++nf) {
            int col = c32 + nf * 16 + (lane & 15);
            float bb = b_in[col];
            #pragma unroll
            for (int rb = 0; rb < 2; ++rb)
                #pragma unroll
                for (int j = 0; j < 4; ++j)
                    hb[(size_t)(r0 + rb * 16 + rowoff + j) * H + col] = f2bf(acc[rb][nf][j] + bb);
        }
    } else {
        // ---- CSR scatter: 4 edges/thread, pipelined atomics ----
        int e0 = (blk - RT) * 1024 + tid;
        int src[4], dst[4];
        float a[4];
        #pragma unroll
        for (int k = 0; k < 4; ++k) {
            int e = e0 + k * 256;
            if (e < E_EDGES) {
                src[k] = ei[e];
                dst[k] = ei[E_EDGES + e];
                a[k] = ea[e];
            } else {
                dst[k] = -1;
            }
        }
        int pos[4];
        #pragma unroll
        for (int k = 0; k < 4; ++k)
            if (dst[k] >= 0) pos[k] = rowptr[dst[k]] + atomicAdd(&fill[dst[k]], 1);
        #pragma unroll
        for (int k = 0; k < 4; ++k)
            if (dst[k] >= 0) csr[pos[k]] = make_uint2((uint_t)src[k], __float_as_uint(a[k]));
    }
}

// ------ qkvs MFMA ------
// pair 0 -> qf8 (fp8 q', 2/ushort) + vb (2 bf16 v / uint), entry e={f, f+16}
// pair 1 -> ks (uint: hi=agg bf16, lo=k' bf16), standard col index
__global__ __launch_bounds__(256) void k_qkvs_mfma(const ushort_t* __restrict__ hb,
                                                   const ushort_t* __restrict__ Bq, // [512][128]
                                                   const float* __restrict__ bk, const float* __restrict__ bq,
                                                   const float* __restrict__ bv, const float* __restrict__ bs,
                                                   ushort_t* __restrict__ qf8, uint_t* __restrict__ vb,
                                                   uint_t* __restrict__ ks)
{
    int gw = blockIdx.x * 4 + (threadIdx.x >> 6);
    int lane = threadIdx.x & 63;
    int rt = gw >> 3, cfg = gw & 7;
    int pair = cfg >> 2, c32 = (cfg & 3) * 32;
    int r0 = rt * 32;
    const ushort_t* Ap = hb + (size_t)(r0 + (lane & 15)) * H + 8 * (lane >> 4);
    int cb0 = pair ? 0   : 128;   // k : q
    int cb1 = pair ? 384 : 256;   // s : v
    const ushort_t* Bp0 = Bq + (size_t)(cb0 + c32 + (lane & 15)) * H + 8 * (lane >> 4);
    const ushort_t* Bp1 = Bq + (size_t)(cb1 + c32 + (lane & 15)) * H + 8 * (lane >> 4);
    f32x4 acc[2][2][2]; // [rb][mat][nf]
    #pragma unroll
    for (int rb = 0; rb < 2; ++rb)
        #pragma unroll
        for (int m = 0; m < 2; ++m)
            #pragma unroll
            for (int nf = 0; nf < 2; ++nf) acc[rb][m][nf] = (f32x4){0.f, 0.f, 0.f, 0.f};
    #pragma unroll
    for (int kk = 0; kk < 4; ++kk) {
        bf16x8 a0 = *(const bf16x8*)(Ap + kk * 32);
        bf16x8 a1 = *(const bf16x8*)(Ap + 16 * H + kk * 32);
        #pragma unroll
        for (int nf = 0; nf < 2; ++nf) {
            bf16x8 b0 = *(const bf16x8*)(Bp0 + nf * 16 * H + kk * 32);
            bf16x8 b1 = *(const bf16x8*)(Bp1 + nf * 16 * H + kk * 32);
            acc[0][0][nf] = __builtin_amdgcn_mfma_f32_16x16x32_bf16(a0, b0, acc[0][0][nf], 0, 0, 0);
            acc[1][0][nf] = __builtin_amdgcn_mfma_f32_16x16x32_bf16(a1, b0, acc[1][0][nf], 0, 0, 0);
            acc[0][1][nf] = __builtin_amdgcn_mfma_f32_16x16x32_bf16(a0, b1, acc[0][1][nf], 0, 0, 0);
            acc[1][1][nf] = __builtin_amdgcn_mfma_f32_16x16x32_bf16(a1, b1, acc[1][1][nf], 0, 0, 0);
        }
    }
    int rowoff = (lane >> 4) << 2;
    int l15 = lane & 15;
    if (pair == 0) {
        int col_lo = c32 + l15, col_hi = col_lo + 16;
        int e = (c32 >> 1) + l15;
        float bql = bq[col_lo], bqh = bq[col_hi];
        float bvl = bv[col_lo], bvh = bv[col_hi];
        #pragma unroll
        for (int rb = 0; rb < 2; ++rb)
            #pragma unroll
            for (int j = 0; j < 4; ++j) {
                size_t row = r0 + rb * 16 + rowoff + j;
                float ql = (acc[rb][0][0][j] + bql) * L2E;
                float qh = (acc[rb][0][1][j] + bqh) * L2E;
                qf8[row * 64 + e] = (ushort_t)fp8_pk(ql, qh);
                uint_t vl = f2bf(acc[rb][1][0][j] + bvl);
                uint_t vh = f2bf(acc[rb][1][1][j] + bvh);
                vb[row * 64 + e] = (vh << 16) | vl;
            }
    } else {
        #pragma unroll
        for (int nf = 0; nf < 2; ++nf) {
            int col = c32 + nf * 16 + l15;
            float bbk = bk[col], bbs = bs[col];
            #pragma unroll
            for (int rb = 0; rb < 2; ++rb)
                #pragma unroll
                for (int j = 0; j < 4; ++j) {
                    size_t row = r0 + rb * 16 + rowoff + j;
                    uint_t kkv = f2bf((acc[rb][0][nf][j] + bbk) * L2E);
                    uint_t ssv = f2bf(acc[rb][1][nf][j] + bbs);
                    ks[row * H + col] = (ssv << 16) | kkv;
                }
        }
    }
}

// ================= CSR scan helpers =================
__global__ __launch_bounds__(256) void k_bsum(const int* __restrict__ deg, int* __restrict__ bsum)
{
    __shared__ int ws[4];
    int t = threadIdx.x;
    int i = blockIdx.x * 256 + t;
    int v = (i < N_NODES) ? deg[i] : 0;
    #pragma unroll
    for (int off = 32; off > 0; off >>= 1) v += __shfl_down(v, off);
    if ((t & 63) == 0) ws[t >> 6] = v;
    __syncthreads();
    if (t == 0) bsum[blockIdx.x] = ws[0] + ws[1] + ws[2] + ws[3];
}

__global__ __launch_bounds__(256) void k_bscan(const int* __restrict__ bsum, int* __restrict__ boff)
{
    __shared__ int ws[4];
    int t = threadIdx.x;
    int v = (t < NBLK) ? bsum[t] : 0;
    int lane = t & 63, wid = t >> 6;
    int inc = v;
    #pragma unroll
    for (int off = 1; off < 64; off <<= 1) {
        int u = __shfl_up(inc, off);
        if (lane >= off) inc += u;
    }
    if (lane == 63) ws[wid] = inc;
    __syncthreads();
    if (t == 0) {
        int s = 0;
        #pragma unroll
        for (int w = 0; w < 4; ++w) { int x = ws[w]; ws[w] = s; s += x; }
    }
    __syncthreads();
    if (t < NBLK) boff[t] = inc - v + ws[wid];
}

__global__ __launch_bounds__(256) void k_rowptr(const int* __restrict__ deg,
                                                const int* __restrict__ boff,
                                                int* __restrict__ rowptr)
{
    __shared__ int ws[4];
    int t = threadIdx.x;
    int i = blockIdx.x * 256 + t;
    int v = (i < N_NODES) ? deg[i] : 0;
    int lane = t & 63, wid = t >> 6;
    int inc = v;
    #pragma unroll
    for (int off = 1; off < 64; off <<= 1) {
        int u = __shfl_up(inc, off);
        if (lane >= off) inc += u;
    }
    if (lane == 63) ws[wid] = inc;
    __syncthreads();
    if (t == 0) {
        int s = 0;
        #pragma unroll
        for (int w = 0; w < 4; ++w) { int x = ws[w]; ws[w] = s; s += x; }
    }
    __syncthreads();
    int excl = inc - v + ws[wid] + boff[blockIdx.x];
    if (i < N_NODES) rowptr[i] = excl;
    if (i == N_NODES - 1) rowptr[N_NODES] = excl + v;
}

// ---- per-edge gate+message (round-11 builtin math: best known good) ----
__device__ __forceinline__ void edge_acc(uint_t qw, uint_t uv, float ea,
                                         f32x2 we2, f32x2 be2, f32x2 kd2, f32x2& acc)
{
    f32x2 q = cvtpk_q(qw);
    f32x2 v;
    v.x = __uint_as_float(uv << 16);
    v.y = __uint_as_float(uv & 0xffff0000u);
    f32x2 av; av.x = ea; av.y = ea;
    f32x2 ep = __builtin_elementwise_fma(av, we2, be2);       // e' (·log2e)
    f32x2 g  = __builtin_elementwise_fma((f32x2){2.f, 2.f}, ep, kd2 + q);
    f32x2 ex; ex.x = EXP2F(-g.x); ex.y = EXP2F(-g.y);
    f32x2 d = ex + (f32x2){1.f, 1.f};
    f32x2 sg; sg.x = __builtin_amdgcn_rcpf(d.x); sg.y = __builtin_amdgcn_rcpf(d.y);
    f32x2 m = __builtin_elementwise_fma((f32x2){LN2, LN2}, ep, v); // v + e
    acc = __builtin_elementwise_fma(sg, m, acc);
}

// ===== aggregation (one wave per dst node) + LayerNorm + GELU -> h (bf16) =====
__global__ __launch_bounds__(256) void k_agg_ln(const int* __restrict__ rowptr,
                                                const uint2* __restrict__ csr,
                                                const ushort_t* __restrict__ qf8,
                                                const uint_t* __restrict__ vb,
                                                const uint_t* __restrict__ ks,
                                                const float* __restrict__ We,
                                                const float* __restrict__ be,
                                                const float* __restrict__ gamma,
                                                const float* __restrict__ beta,
                                                ushort_t* __restrict__ hout)
{
    int tid = threadIdx.x;
    int lane = tid & 63;
    int node = __builtin_amdgcn_readfirstlane(blockIdx.x * 4 + (tid >> 6));
    int flo = ((lane >> 4) << 5) + (lane & 15);
    int fhi = flo + 16;

    f32x2 we2, be2, kd2, acc;
    we2.x = We[flo] * L2E; we2.y = We[fhi] * L2E;
    be2.x = be[flo] * L2E; be2.y = be[fhi] * L2E;
    uint_t klo = ks[(size_t)node * H + flo];
    uint_t khi = ks[(size_t)node * H + fhi];
    kd2.x = bf2f(klo & 0xffffu); kd2.y = bf2f(khi & 0xffffu);   // k' (·log2e)
    acc.x = bf2f(klo >> 16);     acc.y = bf2f(khi >> 16);       // h@Ws + b_gcn
    int p = rowptr[node];        // uniform -> s_load
    int pend = rowptr[node + 1];

#define GATH(QW, UV, A, C) { \
    A = __uint_as_float((C).y); \
    const ushort_t* qrow_ = qf8 + ((size_t)(C).x << 6); \
    const uint_t*   vrow_ = vb  + ((size_t)(C).x << 6); \
    QW = qrow_[lane]; \
    UV = vrow_[lane]; }

    while (p + 8 <= pend) {
        uint2 c0 = csr[p],     c1 = csr[p + 1], c2 = csr[p + 2], c3 = csr[p + 3];
        uint2 c4 = csr[p + 4], c5 = csr[p + 5], c6 = csr[p + 6], c7 = csr[p + 7];
        uint_t w0, w1, w2, w3, w4, w5, w6, w7;
        uint_t u0, u1, u2, u3, u4, u5, u6, u7;
        float a0, a1, a2, a3, a4, a5, a6, a7;
        GATH(w0, u0, a0, c0); GATH(w1, u1, a1, c1); GATH(w2, u2, a2, c2); GATH(w3, u3, a3, c3);
        GATH(w4, u4, a4, c4); GATH(w5, u5, a5, c5); GATH(w6, u6, a6, c6); GATH(w7, u7, a7, c7);
        edge_acc(w0, u0, a0, we2, be2, kd2, acc);
        edge_acc(w1, u1, a1, we2, be2, kd2, acc);
        edge_acc(w2, u2, a2, we2, be2, kd2, acc);
        edge_acc(w3, u3, a3, we2, be2, kd2, acc);
        edge_acc(w4, u4, a4, we2, be2, kd2, acc);
        edge_acc(w5, u5, a5, we2, be2, kd2, acc);
        edge_acc(w6, u6, a6, we2, be2, kd2, acc);
        edge_acc(w7, u7, a7, we2, be2, kd2, acc);
        p += 8;
    }
    if (p + 4 <= pend) {
        uint2 c0 = csr[p], c1 = csr[p + 1], c2 = csr[p + 2], c3 = csr[p + 3];
        uint_t w0, w1, w2, w3;
        uint_t u0, u1, u2, u3;
        float a0, a1, a2, a3;
        GATH(w0, u0, a0, c0); GATH(w1, u1, a1, c1); GATH(w2, u2, a2, c2); GATH(w3, u3, a3, c3);
        edge_acc(w0, u0, a0, we2, be2, kd2, acc);
        edge_acc(w1, u1, a1, we2, be2, kd2, acc);
        edge_acc(w2, u2, a2, we2, be2, kd2, acc);
        edge_acc(w3, u3, a3, we2, be2, kd2, acc);
        p += 4;
    }
    for (; p < pend; ++p) {
        uint2 c = csr[p];
        uint_t qw, uv; float a;
        GATH(qw, uv, a, c);
        edge_acc(qw, uv, a, we2, be2, kd2, acc);
    }
#undef GATH

    float s  = acc.x + acc.y;
    float s2 = acc.x * acc.x + acc.y * acc.y;
    #pragma unroll
    for (int off = 32; off > 0; off >>= 1) {
        s  += __shfl_down(s, off);
        s2 += __shfl_down(s2, off);
    }
    s  = __shfl(s, 0);
    s2 = __shfl(s2, 0);
    float mu  = s * (1.f / H);
    float var = s2 * (1.f / H) - mu * mu;
    float rstd = rsqrtf(var + EPSF);
    float glo = gamma[flo], ghi = gamma[fhi];
    float blo = beta[flo],  bhi = beta[fhi];
    float y0 = (acc.x - mu) * rstd * glo + blo;
    float y1 = (acc.y - mu) * rstd * ghi + bhi;
    y0 = 0.5f * y0 * (1.f + erff(y0 * 0.70710678118f));
    y1 = 0.5f * y1 * (1.f + erff(y1 * 0.70710678118f));
    hout[(size_t)node * H + flo] = f2bf(y0);
    hout[(size_t)node * H + fhi] = f2bf(y1);
}

// ---------------- out_proj MFMA: out = h @ W_out (fp32 out) ----------------
__global__ __launch_bounds__(256) void k_out_mfma(const ushort_t* __restrict__ hb,
                                                  const ushort_t* __restrict__ Bout, // [64][128]
                                                  float* __restrict__ out)
{
    int gw = blockIdx.x * 4 + (threadIdx.x >> 6);
    if (gw >= 6250) return;
    int lane = threadIdx.x & 63;
    int rg = gw >> 1, cg = gw & 1;
    int r0 = rg * 16, c0 = cg * 32;
    const ushort_t* Ap = hb + (size_t)(r0 + (lane & 15)) * H + 8 * (lane >> 4);
    const ushort_t* Bp = Bout + (size_t)(c0 + (lane & 15)) * H + 8 * (lane >> 4);
    f32x4 acc[2];
    acc[0] = (f32x4){0.f, 0.f, 0.f, 0.f};
    acc[1] = (f32x4){0.f, 0.f, 0.f, 0.f};
    #pragma unroll
    for (int kk = 0; kk < 4; ++kk) {
        bf16x8 a = *(const bf16x8*)(Ap + kk * 32);
        bf16x8 b0 = *(const bf16x8*)(Bp + kk * 32);
        bf16x8 b1 = *(const bf16x8*)(Bp + 16 * H + kk * 32);
        acc[0] = __builtin_amdgcn_mfma_f32_16x16x32_bf16(a, b0, acc[0], 0, 0, 0);
        acc[1] = __builtin_amdgcn_mfma_f32_16x16x32_bf16(a, b1, acc[1], 0, 0, 0);
    }
    int rowb = r0 + ((lane >> 4) << 2);
    #pragma unroll
    for (int nf = 0; nf < 2; ++nf) {
        int col = c0 + nf * 16 + (lane & 15);
        #pragma unroll
        for (int j = 0; j < 4; ++j)
            out[(size_t)(rowb + j) * DOUT + col] = acc[nf][j];
    }
}

extern "C" void kernel_launch(void* const* d_in, const int* in_sizes, int n_in,
                              void* d_out, int out_size, void* d_ws, size_t ws_size,
                              hipStream_t stream) {
    const float* x         = (const float*)d_in[0];
    const float* edge_attr = (const float*)d_in[1];
    const float* W_in      = (const float*)d_in[2];
    const float* b_in      = (const float*)d_in[3];
    const float* Wk        = (const float*)d_in[4];
    const float* bk        = (const float*)d_in[5];
    const float* Wq        = (const float*)d_in[6];
    const float* bq        = (const float*)d_in[7];
    const float* Wv        = (const float*)d_in[8];
    const float* bv        = (const float*)d_in[9];
    const float* We        = (const float*)d_in[10];
    const float* be        = (const float*)d_in[11];
    const float* Ws        = (const float*)d_in[12];
    const float* b_gcn     = (const float*)d_in[13];
    const float* gamma     = (const float*)d_in[14];
    const float* beta      = (const float*)d_in[15];
    const float* W_out     = (const float*)d_in[16];
    const int*   edge_index= (const int*)d_in[17];
    float* out = (float*)d_out;

    char* wsb = (char*)d_ws;
    ushort_t* hb  = (ushort_t*)wsb;                  wsb += (size_t)NPAD * H * 2;
    ushort_t* qf8 = (ushort_t*)wsb;                  wsb += (size_t)NPAD * 64 * 2;
    uint_t*   vb  = (uint_t*)wsb;                    wsb += (size_t)NPAD * 64 * 4;
    uint_t*   ks  = (uint_t*)wsb;                    wsb += (size_t)NPAD * H * 4;
    ushort_t* xb  = (ushort_t*)wsb;                  wsb += (size_t)NPAD * DIN * 2;
    ushort_t* Bq  = (ushort_t*)wsb;                  wsb += 3 * 512 * 128 * 2;
    ushort_t* Bin = (ushort_t*)wsb;                  wsb += 128 * 256 * 2;
    ushort_t* Bout= (ushort_t*)wsb;                  wsb += 64 * 128 * 2;
    uint2* csr    = (uint2*)wsb;                     wsb += (size_t)E_EDGES * 8;
    int*   deg    = (int*)wsb;                       wsb += N_NODES * 4;
    int*   fill   = (int*)wsb;                       wsb += N_NODES * 4;
    int*   rowptr = (int*)wsb;                       wsb += (N_NODES + 1) * 4;
    int*   bsum   = (int*)wsb;                       wsb += NBLK * 4;
    int*   boff   = (int*)wsb;                       wsb += NBLK * 4;

    (void)hipMemsetAsync(deg, 0, 2 * N_NODES * sizeof(int), stream); // zeroes deg + fill

    // fused: convx ∥ pack ∥ hist
    k_pre<<<CVB + PKB + HSB, 256, 0, stream>>>(x, xb, Wk, Wq, Wv, Ws, W_in, W_out,
                                               Bq, Bin, Bout, edge_index, deg);
    k_bsum<<<NBLK, 256, 0, stream>>>(deg, bsum);
    k_bscan<<<1, 256, 0, stream>>>(bsum, boff);
    k_rowptr<<<NBLK, 256, 0, stream>>>(deg, boff, rowptr);

    // fused: in_proj MFMA ∥ CSR scatter
    k_mid<<<RT + SCB, 256, 0, stream>>>(xb, Bin, b_in, hb,
                                        edge_index, edge_attr, rowptr, fill, csr);

    for (int l = 0; l < 3; ++l) {
        k_qkvs_mfma<<<2 * RT, 256, 0, stream>>>(hb, Bq + (size_t)l * 512 * 128,
                                                bk + l * H, bq + l * H, bv + l * H, b_gcn + l * H,
                                                qf8, vb, ks);
        k_agg_ln<<<N_NODES / 4, 256, 0, stream>>>(rowptr, csr, qf8, vb, ks,
                                                  We + l * H, be + l * H,
                                                  gamma + l * H, beta + l * H, hb);
    }
    k_out_mfma<<<RT, 256, 0, stream>>>(hb, Bout, out);
}

// Round 16
// 375.584 us; speedup vs baseline: 1.1384x; 1.0673x over previous
//
#include <hip/hip_runtime.h>

#define N_NODES 50000
#define NPAD    50048   // padded row count (multiple of 64) so 32-row tiles need no guard
#define E_EDGES 800000
#define DIN 256
#define H 128
#define DOUT 64
#define EPSF 1e-5f
#define NBLK 196   // ceil(N_NODES/256)
#define RT   1563  // ceil(N_NODES/32) row tiles
#define CVB  12500 // convx blocks
#define PKB  928   // pack blocks
#define HSB  3125  // hist blocks
#define SCB  782   // scatter blocks (4 edges/thread, 1024 edges/block)

typedef __bf16 bf16x8 __attribute__((ext_vector_type(8)));
typedef float  f32x4  __attribute__((ext_vector_type(4)));
typedef float  f32x2  __attribute__((ext_vector_type(2)));
typedef unsigned short ushort_t;
typedef unsigned int   uint_t;

#define L2E 1.4426950408889634f
#define LN2 0.6931471805599453f

#if __has_builtin(__builtin_amdgcn_exp2f)
#define EXP2F(x) __builtin_amdgcn_exp2f(x)
#else
#define EXP2F(x) __expf((x) * LN2)
#endif

__device__ inline float bf2f(uint_t u) {
    union { uint_t i; float f; } v; v.i = u << 16; return v.f;
}
__device__ inline ushort_t f2bf(float f) {
    uint_t u = __float_as_uint(f);
    uint_t r = (u + 0x7fffu + ((u >> 16) & 1u)) >> 16;
    return (ushort_t)r;
}

// ---- fp8 e4m3 helpers (hw path + software fallback) ----
#if __has_builtin(__builtin_amdgcn_cvt_f32_fp8)
#define FP8DEC(u, s) __builtin_amdgcn_cvt_f32_fp8((uint_t)(u), (s))
#else
__device__ inline float fp8_dec_sw(uint_t b) {
    uint_t s = (b & 0x80u) << 24;
    uint_t em = b & 0x7fu;
    if (em < 8u) return __uint_as_float(s);           // FTZ denormals
    uint_t ex = (em >> 3) + 120u;
    uint_t mn = (em & 7u) << 20;
    return __uint_as_float(s | (ex << 23) | mn);
}
#define FP8DEC(u, s) fp8_dec_sw(((uint_t)(u) >> (8 * (s))) & 0xffu)
#endif

// paired fp8 decode: 2 fp8 (low 16 bits) -> 2 floats
#if __has_builtin(__builtin_amdgcn_cvt_pk_f32_fp8)
__device__ __forceinline__ f32x2 cvtpk_q(uint_t u) {
    auto r = __builtin_amdgcn_cvt_pk_f32_fp8(u, false);
    f32x2 o; o.x = r[0]; o.y = r[1]; return o;
}
#else
__device__ __forceinline__ f32x2 cvtpk_q(uint_t u) {
    f32x2 r; r.x = FP8DEC(u, 0); r.y = FP8DEC(u, 1); return r;
}
#endif

#if __has_builtin(__builtin_amdgcn_cvt_pk_fp8_f32)
__device__ inline uint_t fp8_pk(float a, float b) {
    return (uint_t)__builtin_amdgcn_cvt_pk_fp8_f32(a, b, 0, false) & 0xffffu;
}
#else
__device__ inline uint_t fp8_enc_sw(float f) {
    uint_t u = __float_as_uint(f);
    uint_t s = (u >> 24) & 0x80u;
    uint_t a = u & 0x7fffffffu;
    if (a < 0x3c800000u) return s;           // |f| < 2^-6 -> 0
    if (a > 0x43e00000u) a = 0x43e00000u;    // clamp to 448
    uint_t r = a + 0x7ffffu + ((a >> 20) & 1u);
    uint_t ex = (r >> 23) - 120u;
    uint_t mn = (r >> 20) & 7u;
    return s | (ex << 3) | mn;
}
__device__ inline uint_t fp8_pk(float a, float b) {
    return fp8_enc_sw(a) | (fp8_enc_sw(b) << 8);
}
#endif

// ======= fused pre-pass: convx ∥ weight-pack ∥ edge histogram (+rank) =======
__global__ __launch_bounds__(256) void k_pre(const float* __restrict__ x, ushort_t* __restrict__ xb,
                                             const float* __restrict__ Wk, const float* __restrict__ Wq,
                                             const float* __restrict__ Wv, const float* __restrict__ Ws,
                                             const float* __restrict__ W_in, const float* __restrict__ W_out,
                                             ushort_t* __restrict__ Bq, ushort_t* __restrict__ Bin,
                                             ushort_t* __restrict__ Bout,
                                             const int* __restrict__ ei, int* __restrict__ deg,
                                             int* __restrict__ rank)
{
    int b = blockIdx.x;
    int tid = threadIdx.x;
    if (b < CVB) {
        int i = b * 256 + tid;
        float4 v = ((const float4*)x)[i];
        ushort4 o;
        o.x = f2bf(v.x); o.y = f2bf(v.y); o.z = f2bf(v.z); o.w = f2bf(v.w);
        ((ushort4*)xb)[i] = o;
    } else if (b < CVB + PKB) {
        int t = (b - CVB) * 256 + tid;
        if (t < 196608) {
            int l = t >> 16;
            int r = t & 65535;
            int c = r >> 7;
            int k = r & 127;
            int m = c >> 7;
            int cm = c & 127;
            const float* W = (m == 0) ? Wk : (m == 1) ? Wq : (m == 2) ? Wv : Ws;
            Bq[t] = f2bf(W[(size_t)l * H * H + k * H + cm]);
        } else if (t < 229376) {
            int t2 = t - 196608;
            int c = t2 >> 8;
            int k = t2 & 255;
            Bin[t2] = f2bf(W_in[k * H + c]);
        } else {
            int t3 = t - 229376;
            int c = t3 >> 7;
            int k = t3 & 127;
            Bout[t3] = f2bf(W_out[k * DOUT + c]);
        }
    } else {
        int e = (b - CVB - PKB) * 256 + tid;
        int dst = ei[E_EDGES + e];
        rank[e] = atomicAdd(&deg[dst], 1);   // unique slot within dst bucket, for free
    }
}

// ======= fused mid-pass: in_proj MFMA ∥ atomic-free CSR scatter =======
__global__ __launch_bounds__(256) void k_mid(const ushort_t* __restrict__ xb,
                                             const ushort_t* __restrict__ Bin,
                                             const float* __restrict__ b_in,
                                             ushort_t* __restrict__ hb,
                                             const int* __restrict__ ei,
                                             const float* __restrict__ ea,
                                             const int* __restrict__ rowptr,
                                             const int* __restrict__ rank,
                                             uint2* __restrict__ csr)
{
    int blk = blockIdx.x;
    int tid = threadIdx.x;
    if (blk < RT) {
        // ---- in_proj MFMA: 32 rows x 32 cols per wave, K=256 ----
        int gw = blk * 4 + (tid >> 6);
        int lane = tid & 63;
        int rt = gw >> 2, c32 = (gw & 3) * 32;
        int r0 = rt * 32;
        const ushort_t* Ap = xb + (size_t)(r0 + (lane & 15)) * DIN + 8 * (lane >> 4);
        const ushort_t* Bp = Bin + (size_t)(c32 + (lane & 15)) * DIN + 8 * (lane >> 4);
        f32x4 acc[2][2]; // [rb][nf]
        #pragma unroll
        for (int rb = 0; rb < 2; ++rb)
            #pragma unroll
            for (int nf = 0; nf < 2; ++nf) acc[rb][nf] = (f32x4){0.f, 0.f, 0.f, 0.f};
        #pragma unroll
        for (int ks = 0; ks < 8; ++ks) {
            bf16x8 a0 = *(const bf16x8*)(Ap + ks * 32);
            bf16x8 a1 = *(const bf16x8*)(Ap + 16 * DIN + ks * 32);
            bf16x8 b0 = *(const bf16x8*)(Bp + ks * 32);
            bf16x8 b1 = *(const bf16x8*)(Bp + 16 * DIN + ks * 32);
            acc[0][0] = __builtin_amdgcn_mfma_f32_16x16x32_bf16(a0, b0, acc[0][0], 0, 0, 0);
            acc[1][0] = __builtin_amdgcn_mfma_f32_16x16x32_bf16(a1, b0, acc[1][0], 0, 0, 0);
            acc[0][1] = __builtin_amdgcn_mfma_f32_16x16x32_bf16(a0, b1, acc[0][1], 0, 0, 0);
            acc[1][1] = __builtin_amdgcn_mfma_f32_16x16x32_bf16(a1, b1, acc[1][1], 0, 0, 0);
        }
        int rowoff = (lane >> 4) << 2;
        #pragma unroll
        for (int nf = 0; nf < 2; ++nf) {
            int col = c32 + nf * 16 + (lane & 15);
            float bb = b_in[col];
            #pragma unroll
            for (int rb = 0; rb < 2; ++rb)
                #pragma unroll
                for (int j = 0; j < 4; ++j)
                    hb[(size_t)(r0 + rb * 16 + rowoff + j) * H + col] = f2bf(acc[rb][nf][j] + bb);
        }
    } else {
        // ---- CSR scatter: atomic-free (rank precomputed in k_pre) ----
        int e0 = (blk - RT) * 1024 + tid;
        #pragma unroll
        for (int k = 0; k < 4; ++k) {
            int e = e0 + k * 256;
            if (e < E_EDGES) {
                int src = ei[e];
                int dst = ei[E_EDGES + e];
                int pos = rowptr[dst] + rank[e];
                csr[pos] = make_uint2((uint_t)src, __float_as_uint(ea[e]));
            }
        }
    }
}

// ------ qkvs MFMA ------
// pair 0 -> qf8 (fp8 q', 2/ushort) + vb (2 bf16 v / uint), entry e={f, f+16}
// pair 1 -> ks (uint: hi=agg bf16, lo=k' bf16), standard col index
__global__ __launch_bounds__(256) void k_qkvs_mfma(const ushort_t* __restrict__ hb,
                                                   const ushort_t* __restrict__ Bq, // [512][128]
                                                   const float* __restrict__ bk, const float* __restrict__ bq,
                                                   const float* __restrict__ bv, const float* __restrict__ bs,
                                                   ushort_t* __restrict__ qf8, uint_t* __restrict__ vb,
                                                   uint_t* __restrict__ ks)
{
    int gw = blockIdx.x * 4 + (threadIdx.x >> 6);
    int lane = threadIdx.x & 63;
    int rt = gw >> 3, cfg = gw & 7;
    int pair = cfg >> 2, c32 = (cfg & 3) * 32;
    int r0 = rt * 32;
    const ushort_t* Ap = hb + (size_t)(r0 + (lane & 15)) * H + 8 * (lane >> 4);
    int cb0 = pair ? 0   : 128;   // k : q
    int cb1 = pair ? 384 : 256;   // s : v
    const ushort_t* Bp0 = Bq + (size_t)(cb0 + c32 + (lane & 15)) * H + 8 * (lane >> 4);
    const ushort_t* Bp1 = Bq + (size_t)(cb1 + c32 + (lane & 15)) * H + 8 * (lane >> 4);
    f32x4 acc[2][2][2]; // [rb][mat][nf]
    #pragma unroll
    for (int rb = 0; rb < 2; ++rb)
        #pragma unroll
        for (int m = 0; m < 2; ++m)
            #pragma unroll
            for (int nf = 0; nf < 2; ++nf) acc[rb][m][nf] = (f32x4){0.f, 0.f, 0.f, 0.f};
    #pragma unroll
    for (int kk = 0; kk < 4; ++kk) {
        bf16x8 a0 = *(const bf16x8*)(Ap + kk * 32);
        bf16x8 a1 = *(const bf16x8*)(Ap + 16 * H + kk * 32);
        #pragma unroll
        for (int nf = 0; nf < 2; ++nf) {
            bf16x8 b0 = *(const bf16x8*)(Bp0 + nf * 16 * H + kk * 32);
            bf16x8 b1 = *(const bf16x8*)(Bp1 + nf * 16 * H + kk * 32);
            acc[0][0][nf] = __builtin_amdgcn_mfma_f32_16x16x32_bf16(a0, b0, acc[0][0][nf], 0, 0, 0);
            acc[1][0][nf] = __builtin_amdgcn_mfma_f32_16x16x32_bf16(a1, b0, acc[1][0][nf], 0, 0, 0);
            acc[0][1][nf] = __builtin_amdgcn_mfma_f32_16x16x32_bf16(a0, b1, acc[0][1][nf], 0, 0, 0);
            acc[1][1][nf] = __builtin_amdgcn_mfma_f32_16x16x32_bf16(a1, b1, acc[1][1][nf], 0, 0, 0);
        }
    }
    int rowoff = (lane >> 4) << 2;
    int l15 = lane & 15;
    if (pair == 0) {
        int col_lo = c32 + l15, col_hi = col_lo + 16;
        int e = (c32 >> 1) + l15;
        float bql = bq[col_lo], bqh = bq[col_hi];
        float bvl = bv[col_lo], bvh = bv[col_hi];
        #pragma unroll
        for (int rb = 0; rb < 2; ++rb)
            #pragma unroll
            for (int j = 0; j < 4; ++j) {
                size_t row = r0 + rb * 16 + rowoff + j;
                float ql = (acc[rb][0][0][j] + bql) * L2E;
                float qh = (acc[rb][0][1][j] + bqh) * L2E;
                qf8[row * 64 + e] = (ushort_t)fp8_pk(ql, qh);
                uint_t vl = f2bf(acc[rb][1][0][j] + bvl);
                uint_t vh = f2bf(acc[rb][1][1][j] + bvh);
                vb[row * 64 + e] = (vh << 16) | vl;
            }
    } else {
        #pragma unroll
        for (int nf = 0; nf < 2; ++nf) {
            int col = c32 + nf * 16 + l15;
            float bbk = bk[col], bbs = bs[col];
            #pragma unroll
            for (int rb = 0; rb < 2; ++rb)
                #pragma unroll
                for (int j = 0; j < 4; ++j) {
                    size_t row = r0 + rb * 16 + rowoff + j;
                    uint_t kkv = f2bf((acc[rb][0][nf][j] + bbk) * L2E);
                    uint_t ssv = f2bf(acc[rb][1][nf][j] + bbs);
                    ks[row * H + col] = (ssv << 16) | kkv;
                }
        }
    }
}

// ================= CSR scan helpers =================
__global__ __launch_bounds__(256) void k_bsum(const int* __restrict__ deg, int* __restrict__ bsum)
{
    __shared__ int ws[4];
    int t = threadIdx.x;
    int i = blockIdx.x * 256 + t;
    int v = (i < N_NODES) ? deg[i] : 0;
    #pragma unroll
    for (int off = 32; off > 0; off >>= 1) v += __shfl_down(v, off);
    if ((t & 63) == 0) ws[t >> 6] = v;
    __syncthreads();
    if (t == 0) bsum[blockIdx.x] = ws[0] + ws[1] + ws[2] + ws[3];
}

__global__ __launch_bounds__(256) void k_bscan(const int* __restrict__ bsum, int* __restrict__ boff)
{
    __shared__ int ws[4];
    int t = threadIdx.x;
    int v = (t < NBLK) ? bsum[t] : 0;
    int lane = t & 63, wid = t >> 6;
    int inc = v;
    #pragma unroll
    for (int off = 1; off < 64; off <<= 1) {
        int u = __shfl_up(inc, off);
        if (lane >= off) inc += u;
    }
    if (lane == 63) ws[wid] = inc;
    __syncthreads();
    if (t == 0) {
        int s = 0;
        #pragma unroll
        for (int w = 0; w < 4; ++w) { int x = ws[w]; ws[w] = s; s += x; }
    }
    __syncthreads();
    if (t < NBLK) boff[t] = inc - v + ws[wid];
}

__global__ __launch_bounds__(256) void k_rowptr(const int* __restrict__ deg,
                                                const int* __restrict__ boff,
                                                int* __restrict__ rowptr)
{
    __shared__ int ws[4];
    int t = threadIdx.x;
    int i = blockIdx.x * 256 + t;
    int v = (i < N_NODES) ? deg[i] : 0;
    int lane = t & 63, wid = t >> 6;
    int inc = v;
    #pragma unroll
    for (int off = 1; off < 64; off <<= 1) {
        int u = __shfl_up(inc, off);
        if (lane >= off) inc += u;
    }
    if (lane == 63) ws[wid] = inc;
    __syncthreads();
    if (t == 0) {
        int s = 0;
        #pragma unroll
        for (int w = 0; w < 4; ++w) { int x = ws[w]; ws[w] = s; s += x; }
    }
    __syncthreads();
    int excl = inc - v + ws[wid] + boff[blockIdx.x];
    if (i < N_NODES) rowptr[i] = excl;
    if (i == N_NODES - 1) rowptr[N_NODES] = excl + v;
}

// ---- per-edge gate+message (round-11 builtin math: best known good) ----
__device__ __forceinline__ void edge_acc(uint_t qw, uint_t uv, float ea,
                                         f32x2 we2, f32x2 be2, f32x2 kd2, f32x2& acc)
{
    f32x2 q = cvtpk_q(qw);
    f32x2 v;
    v.x = __uint_as_float(uv << 16);
    v.y = __uint_as_float(uv & 0xffff0000u);
    f32x2 av; av.x = ea; av.y = ea;
    f32x2 ep = __builtin_elementwise_fma(av, we2, be2);       // e' (·log2e)
    f32x2 g  = __builtin_elementwise_fma((f32x2){2.f, 2.f}, ep, kd2 + q);
    f32x2 ex; ex.x = EXP2F(-g.x); ex.y = EXP2F(-g.y);
    f32x2 d = ex + (f32x2){1.f, 1.f};
    f32x2 sg; sg.x = __builtin_amdgcn_rcpf(d.x); sg.y = __builtin_amdgcn_rcpf(d.y);
    f32x2 m = __builtin_elementwise_fma((f32x2){LN2, LN2}, ep, v); // v + e
    acc = __builtin_elementwise_fma(sg, m, acc);
}

// ===== aggregation (one wave per dst node) + LayerNorm + GELU -> h (bf16) =====
__global__ __launch_bounds__(256) void k_agg_ln(const int* __restrict__ rowptr,
                                                const uint2* __restrict__ csr,
                                                const ushort_t* __restrict__ qf8,
                                                const uint_t* __restrict__ vb,
                                                const uint_t* __restrict__ ks,
                                                const float* __restrict__ We,
                                                const float* __restrict__ be,
                                                const float* __restrict__ gamma,
                                                const float* __restrict__ beta,
                                                ushort_t* __restrict__ hout)
{
    int tid = threadIdx.x;
    int lane = tid & 63;
    int node = __builtin_amdgcn_readfirstlane(blockIdx.x * 4 + (tid >> 6));
    int flo = ((lane >> 4) << 5) + (lane & 15);
    int fhi = flo + 16;

    f32x2 we2, be2, kd2, acc;
    we2.x = We[flo] * L2E; we2.y = We[fhi] * L2E;
    be2.x = be[flo] * L2E; be2.y = be[fhi] * L2E;
    uint_t klo = ks[(size_t)node * H + flo];
    uint_t khi = ks[(size_t)node * H + fhi];
    kd2.x = bf2f(klo & 0xffffu); kd2.y = bf2f(khi & 0xffffu);   // k' (·log2e)
    acc.x = bf2f(klo >> 16);     acc.y = bf2f(khi >> 16);       // h@Ws + b_gcn
    int p = rowptr[node];        // uniform -> s_load
    int pend = rowptr[node + 1];

#define GATH(QW, UV, A, C) { \
    A = __uint_as_float((C).y); \
    const ushort_t* qrow_ = qf8 + ((size_t)(C).x << 6); \
    const uint_t*   vrow_ = vb  + ((size_t)(C).x << 6); \
    QW = qrow_[lane]; \
    UV = vrow_[lane]; }

    while (p + 8 <= pend) {
        uint2 c0 = csr[p],     c1 = csr[p + 1], c2 = csr[p + 2], c3 = csr[p + 3];
        uint2 c4 = csr[p + 4], c5 = csr[p + 5], c6 = csr[p + 6], c7 = csr[p + 7];
        uint_t w0, w1, w2, w3, w4, w5, w6, w7;
        uint_t u0, u1, u2, u3, u4, u5, u6, u7;
        float a0, a1, a2, a3, a4, a5, a6, a7;
        GATH(w0, u0, a0, c0); GATH(w1, u1, a1, c1); GATH(w2, u2, a2, c2); GATH(w3, u3, a3, c3);
        GATH(w4, u4, a4, c4); GATH(w5, u5, a5, c5); GATH(w6, u6, a6, c6); GATH(w7, u7, a7, c7);
        edge_acc(w0, u0, a0, we2, be2, kd2, acc);
        edge_acc(w1, u1, a1, we2, be2, kd2, acc);
        edge_acc(w2, u2, a2, we2, be2, kd2, acc);
        edge_acc(w3, u3, a3, we2, be2, kd2, acc);
        edge_acc(w4, u4, a4, we2, be2, kd2, acc);
        edge_acc(w5, u5, a5, we2, be2, kd2, acc);
        edge_acc(w6, u6, a6, we2, be2, kd2, acc);
        edge_acc(w7, u7, a7, we2, be2, kd2, acc);
        p += 8;
    }
    if (p + 4 <= pend) {
        uint2 c0 = csr[p], c1 = csr[p + 1], c2 = csr[p + 2], c3 = csr[p + 3];
        uint_t w0, w1, w2, w3;
        uint_t u0, u1, u2, u3;
        float a0, a1, a2, a3;
        GATH(w0, u0, a0, c0); GATH(w1, u1, a1, c1); GATH(w2, u2, a2, c2); GATH(w3, u3, a3, c3);
        edge_acc(w0, u0, a0, we2, be2, kd2, acc);
        edge_acc(w1, u1, a1, we2, be2, kd2, acc);
        edge_acc(w2, u2, a2, we2, be2, kd2, acc);
        edge_acc(w3, u3, a3, we2, be2, kd2, acc);
        p += 4;
    }
    for (; p < pend; ++p) {
        uint2 c = csr[p];
        uint_t qw, uv; float a;
        GATH(qw, uv, a, c);
        edge_acc(qw, uv, a, we2, be2, kd2, acc);
    }
#undef GATH

    float s  = acc.x + acc.y;
    float s2 = acc.x * acc.x + acc.y * acc.y;
    #pragma unroll
    for (int off = 32; off > 0; off >>= 1) {
        s  += __shfl_down(s, off);
        s2 += __shfl_down(s2, off);
    }
    s  = __shfl(s, 0);
    s2 = __shfl(s2, 0);
    float mu  = s * (1.f / H);
    float var = s2 * (1.f / H) - mu * mu;
    float rstd = rsqrtf(var + EPSF);
    float glo = gamma[flo], ghi = gamma[fhi];
    float blo = beta[flo],  bhi = beta[fhi];
    float y0 = (acc.x - mu) * rstd * glo + blo;
    float y1 = (acc.y - mu) * rstd * ghi + bhi;
    y0 = 0.5f * y0 * (1.f + erff(y0 * 0.70710678118f));
    y1 = 0.5f * y1 * (1.f + erff(y1 * 0.70710678118f));
    hout[(size_t)node * H + flo] = f2bf(y0);
    hout[(size_t)node * H + fhi] = f2bf(y1);
}

// ---------------- out_proj MFMA: out = h @ W_out (fp32 out) ----------------
__global__ __launch_bounds__(256) void k_out_mfma(const ushort_t* __restrict__ hb,
                                                  const ushort_t* __restrict__ Bout, // [64][128]
                                                  float* __restrict__ out)
{
    int gw = blockIdx.x * 4 + (threadIdx.x >> 6);
    if (gw >= 6250) return;
    int lane = threadIdx.x & 63;
    int rg = gw >> 1, cg = gw & 1;
    int r0 = rg * 16, c0 = cg * 32;
    const ushort_t* Ap = hb + (size_t)(r0 + (lane & 15)) * H + 8 * (lane >> 4);
    const ushort_t* Bp = Bout + (size_t)(c0 + (lane & 15)) * H + 8 * (lane >> 4);
    f32x4 acc[2];
    acc[0] = (f32x4){0.f, 0.f, 0.f, 0.f};
    acc[1] = (f32x4){0.f, 0.f, 0.f, 0.f};
    #pragma unroll
    for (int kk = 0; kk < 4; ++kk) {
        bf16x8 a = *(const bf16x8*)(Ap + kk * 32);
        bf16x8 b0 = *(const bf16x8*)(Bp + kk * 32);
        bf16x8 b1 = *(const bf16x8*)(Bp + 16 * H + kk * 32);
        acc[0] = __builtin_amdgcn_mfma_f32_16x16x32_bf16(a, b0, acc[0], 0, 0, 0);
        acc[1] = __builtin_amdgcn_mfma_f32_16x16x32_bf16(a, b1, acc[1], 0, 0, 0);
    }
    int rowb = r0 + ((lane >> 4) << 2);
    #pragma unroll
    for (int nf = 0; nf < 2; ++nf) {
        int col = c0 + nf * 16 + (lane & 15);
        #pragma unroll
        for (int j = 0; j < 4; ++j)
            out[(size_t)(rowb + j) * DOUT + col] = acc[nf][j];
    }
}

extern "C" void kernel_launch(void* const* d_in, const int* in_sizes, int n_in,
                              void* d_out, int out_size, void* d_ws, size_t ws_size,
                              hipStream_t stream) {
    const float* x         = (const float*)d_in[0];
    const float* edge_attr = (const float*)d_in[1];
    const float* W_in      = (const float*)d_in[2];
    const float* b_in      = (const float*)d_in[3];
    const float* Wk        = (const float*)d_in[4];
    const float* bk        = (const float*)d_in[5];
    const float* Wq        = (const float*)d_in[6];
    const float* bq        = (const float*)d_in[7];
    const float* Wv        = (const float*)d_in[8];
    const float* bv        = (const float*)d_in[9];
    const float* We        = (const float*)d_in[10];
    const float* be        = (const float*)d_in[11];
    const float* Ws        = (const float*)d_in[12];
    const float* b_gcn     = (const float*)d_in[13];
    const float* gamma     = (const float*)d_in[14];
    const float* beta      = (const float*)d_in[15];
    const float* W_out     = (const float*)d_in[16];
    const int*   edge_index= (const int*)d_in[17];
    float* out = (float*)d_out;

    char* wsb = (char*)d_ws;
    ushort_t* hb  = (ushort_t*)wsb;                  wsb += (size_t)NPAD * H * 2;
    ushort_t* qf8 = (ushort_t*)wsb;                  wsb += (size_t)NPAD * 64 * 2;
    uint_t*   vb  = (uint_t*)wsb;                    wsb += (size_t)NPAD * 64 * 4;
    uint_t*   ks  = (uint_t*)wsb;                    wsb += (size_t)NPAD * H * 4;
    ushort_t* xb  = (ushort_t*)wsb;                  wsb += (size_t)NPAD * DIN * 2;
    ushort_t* Bq  = (ushort_t*)wsb;                  wsb += 3 * 512 * 128 * 2;
    ushort_t* Bin = (ushort_t*)wsb;                  wsb += 128 * 256 * 2;
    ushort_t* Bout= (ushort_t*)wsb;                  wsb += 64 * 128 * 2;
    uint2* csr    = (uint2*)wsb;                     wsb += (size_t)E_EDGES * 8;
    int*   rank   = (int*)wsb;                       wsb += (size_t)E_EDGES * 4;
    int*   deg    = (int*)wsb;                       wsb += N_NODES * 4;
    int*   rowptr = (int*)wsb;                       wsb += (N_NODES + 1) * 4;
    int*   bsum   = (int*)wsb;                       wsb += NBLK * 4;
    int*   boff   = (int*)wsb;                       wsb += NBLK * 4;

    (void)hipMemsetAsync(deg, 0, N_NODES * sizeof(int), stream);

    // fused: convx ∥ pack ∥ hist(+rank)
    k_pre<<<CVB + PKB + HSB, 256, 0, stream>>>(x, xb, Wk, Wq, Wv, Ws, W_in, W_out,
                                               Bq, Bin, Bout, edge_index, deg, rank);
    k_bsum<<<NBLK, 256, 0, stream>>>(deg, bsum);
    k_bscan<<<1, 256, 0, stream>>>(bsum, boff);
    k_rowptr<<<NBLK, 256, 0, stream>>>(deg, boff, rowptr);

    // fused: in_proj MFMA ∥ atomic-free CSR scatter
    k_mid<<<RT + SCB, 256, 0, stream>>>(xb, Bin, b_in, hb,
                                        edge_index, edge_attr, rowptr, rank, csr);

    for (int l = 0; l < 3; ++l) {
        k_qkvs_mfma<<<2 * RT, 256, 0, stream>>>(hb, Bq + (size_t)l * 512 * 128,
                                                bk + l * H, bq + l * H, bv + l * H, b_gcn + l * H,
                                                qf8, vb, ks);
        k_agg_ln<<<N_NODES / 4, 256, 0, stream>>>(rowptr, csr, qf8, vb, ks,
                                                  We + l * H, be + l * H,
                                                  gamma + l * H, beta + l * H, hb);
    }
    k_out_mfma<<<RT, 256, 0, stream>>>(hb, Bout, out);
}

// Round 17
// 373.971 us; speedup vs baseline: 1.1433x; 1.0043x over previous
//
#include <hip/hip_runtime.h>

#define N_NODES 50000
#define NPAD    50048   // padded row count (multiple of 64) so 32-row tiles need no guard
#define E_EDGES 800000
#define DIN 256
#define H 128
#define DOUT 64
#define EPSF 1e-5f
#define NBLK 196   // ceil(N_NODES/256)
#define RT   1563  // ceil(N_NODES/32) row tiles
#define CVB  12500 // convx blocks
#define PKB  928   // pack blocks
#define HSB  3125  // hist blocks
#define SCB  782   // scatter blocks (4 edges/thread, 1024 edges/block)
#define NSHARD 8
#define SHARD_SZ 100000  // E_EDGES / NSHARD

typedef __bf16 bf16x8 __attribute__((ext_vector_type(8)));
typedef float  f32x4  __attribute__((ext_vector_type(4)));
typedef float  f32x2  __attribute__((ext_vector_type(2)));
typedef unsigned short ushort_t;
typedef unsigned int   uint_t;

#define L2E 1.4426950408889634f
#define LN2 0.6931471805599453f

#if __has_builtin(__builtin_amdgcn_exp2f)
#define EXP2F(x) __builtin_amdgcn_exp2f(x)
#else
#define EXP2F(x) __expf((x) * LN2)
#endif

__device__ inline float bf2f(uint_t u) {
    union { uint_t i; float f; } v; v.i = u << 16; return v.f;
}
__device__ inline ushort_t f2bf(float f) {
    uint_t u = __float_as_uint(f);
    uint_t r = (u + 0x7fffu + ((u >> 16) & 1u)) >> 16;
    return (ushort_t)r;
}

// ---- fp8 e4m3 helpers (hw path + software fallback) ----
#if __has_builtin(__builtin_amdgcn_cvt_f32_fp8)
#define FP8DEC(u, s) __builtin_amdgcn_cvt_f32_fp8((uint_t)(u), (s))
#else
__device__ inline float fp8_dec_sw(uint_t b) {
    uint_t s = (b & 0x80u) << 24;
    uint_t em = b & 0x7fu;
    if (em < 8u) return __uint_as_float(s);           // FTZ denormals
    uint_t ex = (em >> 3) + 120u;
    uint_t mn = (em & 7u) << 20;
    return __uint_as_float(s | (ex << 23) | mn);
}
#define FP8DEC(u, s) fp8_dec_sw(((uint_t)(u) >> (8 * (s))) & 0xffu)
#endif

// paired fp8 decode: 2 fp8 (low 16 bits) -> 2 floats
#if __has_builtin(__builtin_amdgcn_cvt_pk_f32_fp8)
__device__ __forceinline__ f32x2 cvtpk_q(uint_t u) {
    auto r = __builtin_amdgcn_cvt_pk_f32_fp8(u, false);
    f32x2 o; o.x = r[0]; o.y = r[1]; return o;
}
#else
__device__ __forceinline__ f32x2 cvtpk_q(uint_t u) {
    f32x2 r; r.x = FP8DEC(u, 0); r.y = FP8DEC(u, 1); return r;
}
#endif

#if __has_builtin(__builtin_amdgcn_cvt_pk_fp8_f32)
__device__ inline uint_t fp8_pk(float a, float b) {
    return (uint_t)__builtin_amdgcn_cvt_pk_fp8_f32(a, b, 0, false) & 0xffffu;
}
#else
__device__ inline uint_t fp8_enc_sw(float f) {
    uint_t u = __float_as_uint(f);
    uint_t s = (u >> 24) & 0x80u;
    uint_t a = u & 0x7fffffffu;
    if (a < 0x3c800000u) return s;           // |f| < 2^-6 -> 0
    if (a > 0x43e00000u) a = 0x43e00000u;    // clamp to 448
    uint_t r = a + 0x7ffffu + ((a >> 20) & 1u);
    uint_t ex = (r >> 23) - 120u;
    uint_t mn = (r >> 20) & 7u;
    return s | (ex << 3) | mn;
}
__device__ inline uint_t fp8_pk(float a, float b) {
    return fp8_enc_sw(a) | (fp8_enc_sw(b) << 8);
}
#endif

// ======= fused pre-pass: convx ∥ weight-pack ∥ sharded edge histogram =======
__global__ __launch_bounds__(256) void k_pre(const float* __restrict__ x, ushort_t* __restrict__ xb,
                                             const float* __restrict__ Wk, const float* __restrict__ Wq,
                                             const float* __restrict__ Wv, const float* __restrict__ Ws,
                                             const float* __restrict__ W_in, const float* __restrict__ W_out,
                                             ushort_t* __restrict__ Bq, ushort_t* __restrict__ Bin,
                                             ushort_t* __restrict__ Bout,
                                             const int* __restrict__ ei, int* __restrict__ deg8,
                                             int* __restrict__ rank)
{
    int b = blockIdx.x;
    int tid = threadIdx.x;
    if (b < CVB) {
        int i = b * 256 + tid;
        float4 v = ((const float4*)x)[i];
        ushort4 o;
        o.x = f2bf(v.x); o.y = f2bf(v.y); o.z = f2bf(v.z); o.w = f2bf(v.w);
        ((ushort4*)xb)[i] = o;
    } else if (b < CVB + PKB) {
        int t = (b - CVB) * 256 + tid;
        if (t < 196608) {
            int l = t >> 16;
            int r = t & 65535;
            int c = r >> 7;
            int k = r & 127;
            int m = c >> 7;
            int cm = c & 127;
            const float* W = (m == 0) ? Wk : (m == 1) ? Wq : (m == 2) ? Wv : Ws;
            Bq[t] = f2bf(W[(size_t)l * H * H + k * H + cm]);
        } else if (t < 229376) {
            int t2 = t - 196608;
            int c = t2 >> 8;
            int k = t2 & 255;
            Bin[t2] = f2bf(W_in[k * H + c]);
        } else {
            int t3 = t - 229376;
            int c = t3 >> 7;
            int k = t3 & 127;
            Bout[t3] = f2bf(W_out[k * DOUT + c]);
        }
    } else {
        int e = (b - CVB - PKB) * 256 + tid;
        int dst = ei[E_EDGES + e];
        int shard = e / SHARD_SZ;            // 8-way contention split
        rank[e] = atomicAdd(&deg8[shard * N_NODES + dst], 1);
    }
}

// ======= fused mid-pass: in_proj MFMA ∥ atomic-free CSR scatter =======
// deg8 now holds ABSOLUTE per-shard bases (rowptr folded in by k_rowptr).
__global__ __launch_bounds__(256) void k_mid(const ushort_t* __restrict__ xb,
                                             const ushort_t* __restrict__ Bin,
                                             const float* __restrict__ b_in,
                                             ushort_t* __restrict__ hb,
                                             const int* __restrict__ ei,
                                             const float* __restrict__ ea,
                                             const int* __restrict__ deg8,
                                             const int* __restrict__ rank,
                                             uint2* __restrict__ csr)
{
    int blk = blockIdx.x;
    int tid = threadIdx.x;
    if (blk < RT) {
        // ---- in_proj MFMA: 32 rows x 32 cols per wave, K=256 ----
        int gw = blk * 4 + (tid >> 6);
        int lane = tid & 63;
        int rt = gw >> 2, c32 = (gw & 3) * 32;
        int r0 = rt * 32;
        const ushort_t* Ap = xb + (size_t)(r0 + (lane & 15)) * DIN + 8 * (lane >> 4);
        const ushort_t* Bp = Bin + (size_t)(c32 + (lane & 15)) * DIN + 8 * (lane >> 4);
        f32x4 acc[2][2]; // [rb][nf]
        #pragma unroll
        for (int rb = 0; rb < 2; ++rb)
            #pragma unroll
            for (int nf = 0; nf < 2; ++nf) acc[rb][nf] = (f32x4){0.f, 0.f, 0.f, 0.f};
        #pragma unroll
        for (int ks = 0; ks < 8; ++ks) {
            bf16x8 a0 = *(const bf16x8*)(Ap + ks * 32);
            bf16x8 a1 = *(const bf16x8*)(Ap + 16 * DIN + ks * 32);
            bf16x8 b0 = *(const bf16x8*)(Bp + ks * 32);
            bf16x8 b1 = *(const bf16x8*)(Bp + 16 * DIN + ks * 32);
            acc[0][0] = __builtin_amdgcn_mfma_f32_16x16x32_bf16(a0, b0, acc[0][0], 0, 0, 0);
            acc[1][0] = __builtin_amdgcn_mfma_f32_16x16x32_bf16(a1, b0, acc[1][0], 0, 0, 0);
            acc[0][1] = __builtin_amdgcn_mfma_f32_16x16x32_bf16(a0, b1, acc[0][1], 0, 0, 0);
            acc[1][1] = __builtin_amdgcn_mfma_f32_16x16x32_bf16(a1, b1, acc[1][1], 0, 0, 0);
        }
        int rowoff = (lane >> 4) << 2;
        #pragma unroll
        for (int nf = 0; nf < 2; ++nf) {
            int col = c32 + nf * 16 + (lane & 15);
            float bb = b_in[col];
            #pragma unroll
            for (int rb = 0; rb < 2; ++rb)
                #pragma unroll
                for (int j = 0; j < 4; ++j)
                    hb[(size_t)(r0 + rb * 16 + rowoff + j) * H + col] = f2bf(acc[rb][nf][j] + bb);
        }
    } else {
        // ---- CSR scatter: atomic-free (absolute shard base + rank) ----
        int e0 = (blk - RT) * 1024 + tid;
        #pragma unroll
        for (int k = 0; k < 4; ++k) {
            int e = e0 + k * 256;
            if (e < E_EDGES) {
                int src = ei[e];
                int dst = ei[E_EDGES + e];
                int shard = e / SHARD_SZ;
                int pos = deg8[shard * N_NODES + dst] + rank[e];
                csr[pos] = make_uint2((uint_t)src, __float_as_uint(ea[e]));
            }
        }
    }
}

// ------ qkvs MFMA ------
// pair 0 -> qf8 (fp8 q', 2/ushort) + vb (2 bf16 v / uint), entry e={f, f+16}
// pair 1 -> ks (uint: hi=agg bf16, lo=k' bf16), standard col index
__global__ __launch_bounds__(256) void k_qkvs_mfma(const ushort_t* __restrict__ hb,
                                                   const ushort_t* __restrict__ Bq, // [512][128]
                                                   const float* __restrict__ bk, const float* __restrict__ bq,
                                                   const float* __restrict__ bv, const float* __restrict__ bs,
                                                   ushort_t* __restrict__ qf8, uint_t* __restrict__ vb,
                                                   uint_t* __restrict__ ks)
{
    int gw = blockIdx.x * 4 + (threadIdx.x >> 6);
    int lane = threadIdx.x & 63;
    int rt = gw >> 3, cfg = gw & 7;
    int pair = cfg >> 2, c32 = (cfg & 3) * 32;
    int r0 = rt * 32;
    const ushort_t* Ap = hb + (size_t)(r0 + (lane & 15)) * H + 8 * (lane >> 4);
    int cb0 = pair ? 0   : 128;   // k : q
    int cb1 = pair ? 384 : 256;   // s : v
    const ushort_t* Bp0 = Bq + (size_t)(cb0 + c32 + (lane & 15)) * H + 8 * (lane >> 4);
    const ushort_t* Bp1 = Bq + (size_t)(cb1 + c32 + (lane & 15)) * H + 8 * (lane >> 4);
    f32x4 acc[2][2][2]; // [rb][mat][nf]
    #pragma unroll
    for (int rb = 0; rb < 2; ++rb)
        #pragma unroll
        for (int m = 0; m < 2; ++m)
            #pragma unroll
            for (int nf = 0; nf < 2; ++nf) acc[rb][m][nf] = (f32x4){0.f, 0.f, 0.f, 0.f};
    #pragma unroll
    for (int kk = 0; kk < 4; ++kk) {
        bf16x8 a0 = *(const bf16x8*)(Ap + kk * 32);
        bf16x8 a1 = *(const bf16x8*)(Ap + 16 * H + kk * 32);
        #pragma unroll
        for (int nf = 0; nf < 2; ++nf) {
            bf16x8 b0 = *(const bf16x8*)(Bp0 + nf * 16 * H + kk * 32);
            bf16x8 b1 = *(const bf16x8*)(Bp1 + nf * 16 * H + kk * 32);
            acc[0][0][nf] = __builtin_amdgcn_mfma_f32_16x16x32_bf16(a0, b0, acc[0][0][nf], 0, 0, 0);
            acc[1][0][nf] = __builtin_amdgcn_mfma_f32_16x16x32_bf16(a1, b0, acc[1][0][nf], 0, 0, 0);
            acc[0][1][nf] = __builtin_amdgcn_mfma_f32_16x16x32_bf16(a0, b1, acc[0][1][nf], 0, 0, 0);
            acc[1][1][nf] = __builtin_amdgcn_mfma_f32_16x16x32_bf16(a1, b1, acc[1][1][nf], 0, 0, 0);
        }
    }
    int rowoff = (lane >> 4) << 2;
    int l15 = lane & 15;
    if (pair == 0) {
        int col_lo = c32 + l15, col_hi = col_lo + 16;
        int e = (c32 >> 1) + l15;
        float bql = bq[col_lo], bqh = bq[col_hi];
        float bvl = bv[col_lo], bvh = bv[col_hi];
        #pragma unroll
        for (int rb = 0; rb < 2; ++rb)
            #pragma unroll
            for (int j = 0; j < 4; ++j) {
                size_t row = r0 + rb * 16 + rowoff + j;
                float ql = (acc[rb][0][0][j] + bql) * L2E;
                float qh = (acc[rb][0][1][j] + bqh) * L2E;
                qf8[row * 64 + e] = (ushort_t)fp8_pk(ql, qh);
                uint_t vl = f2bf(acc[rb][1][0][j] + bvl);
                uint_t vh = f2bf(acc[rb][1][1][j] + bvh);
                vb[row * 64 + e] = (vh << 16) | vl;
            }
    } else {
        #pragma unroll
        for (int nf = 0; nf < 2; ++nf) {
            int col = c32 + nf * 16 + l15;
            float bbk = bk[col], bbs = bs[col];
            #pragma unroll
            for (int rb = 0; rb < 2; ++rb)
                #pragma unroll
                for (int j = 0; j < 4; ++j) {
                    size_t row = r0 + rb * 16 + rowoff + j;
                    uint_t kkv = f2bf((acc[rb][0][nf][j] + bbk) * L2E);
                    uint_t ssv = f2bf(acc[rb][1][nf][j] + bbs);
                    ks[row * H + col] = (ssv << 16) | kkv;
                }
        }
    }
}

// ================= CSR scan helpers (8-shard aware) =================
__global__ __launch_bounds__(256) void k_bsum(const int* __restrict__ deg8, int* __restrict__ bsum)
{
    __shared__ int ws[4];
    int t = threadIdx.x;
    int i = blockIdx.x * 256 + t;
    int v = 0;
    if (i < N_NODES) {
        #pragma unroll
        for (int s = 0; s < NSHARD; ++s) v += deg8[s * N_NODES + i];
    }
    #pragma unroll
    for (int off = 32; off > 0; off >>= 1) v += __shfl_down(v, off);
    if ((t & 63) == 0) ws[t >> 6] = v;
    __syncthreads();
    if (t == 0) bsum[blockIdx.x] = ws[0] + ws[1] + ws[2] + ws[3];
}

__global__ __launch_bounds__(256) void k_bscan(const int* __restrict__ bsum, int* __restrict__ boff)
{
    __shared__ int ws[4];
    int t = threadIdx.x;
    int v = (t < NBLK) ? bsum[t] : 0;
    int lane = t & 63, wid = t >> 6;
    int inc = v;
    #pragma unroll
    for (int off = 1; off < 64; off <<= 1) {
        int u = __shfl_up(inc, off);
        if (lane >= off) inc += u;
    }
    if (lane == 63) ws[wid] = inc;
    __syncthreads();
    if (t == 0) {
        int s = 0;
        #pragma unroll
        for (int w = 0; w < 4; ++w) { int x = ws[w]; ws[w] = s; s += x; }
    }
    __syncthreads();
    if (t < NBLK) boff[t] = inc - v + ws[wid];
}

// computes rowptr AND converts deg8 counts -> absolute per-shard bases in-place
__global__ __launch_bounds__(256) void k_rowptr(int* __restrict__ deg8,
                                                const int* __restrict__ boff,
                                                int* __restrict__ rowptr)
{
    __shared__ int ws[4];
    int t = threadIdx.x;
    int i = blockIdx.x * 256 + t;
    int d[NSHARD];
    int v = 0;
    if (i < N_NODES) {
        #pragma unroll
        for (int s = 0; s < NSHARD; ++s) { d[s] = deg8[s * N_NODES + i]; v += d[s]; }
    }
    int lane = t & 63, wid = t >> 6;
    int inc = v;
    #pragma unroll
    for (int off = 1; off < 64; off <<= 1) {
        int u = __shfl_up(inc, off);
        if (lane >= off) inc += u;
    }
    if (lane == 63) ws[wid] = inc;
    __syncthreads();
    if (t == 0) {
        int s = 0;
        #pragma unroll
        for (int w = 0; w < 4; ++w) { int x = ws[w]; ws[w] = s; s += x; }
    }
    __syncthreads();
    int excl = inc - v + ws[wid] + boff[blockIdx.x];
    if (i < N_NODES) {
        rowptr[i] = excl;
        int run = excl;
        #pragma unroll
        for (int s = 0; s < NSHARD; ++s) { int dd = d[s]; deg8[s * N_NODES + i] = run; run += dd; }
    }
    if (i == N_NODES - 1) rowptr[N_NODES] = excl + v;
}

// ---- per-edge gate+message (round-11 builtin math: best known good) ----
__device__ __forceinline__ void edge_acc(uint_t qw, uint_t uv, float ea,
                                         f32x2 we2, f32x2 be2, f32x2 kd2, f32x2& acc)
{
    f32x2 q = cvtpk_q(qw);
    f32x2 v;
    v.x = __uint_as_float(uv << 16);
    v.y = __uint_as_float(uv & 0xffff0000u);
    f32x2 av; av.x = ea; av.y = ea;
    f32x2 ep = __builtin_elementwise_fma(av, we2, be2);       // e' (·log2e)
    f32x2 g  = __builtin_elementwise_fma((f32x2){2.f, 2.f}, ep, kd2 + q);
    f32x2 ex; ex.x = EXP2F(-g.x); ex.y = EXP2F(-g.y);
    f32x2 d = ex + (f32x2){1.f, 1.f};
    f32x2 sg; sg.x = __builtin_amdgcn_rcpf(d.x); sg.y = __builtin_amdgcn_rcpf(d.y);
    f32x2 m = __builtin_elementwise_fma((f32x2){LN2, LN2}, ep, v); // v + e
    acc = __builtin_elementwise_fma(sg, m, acc);
}

// ===== aggregation (one wave per dst node) + LayerNorm + GELU -> h (bf16) =====
__global__ __launch_bounds__(256) void k_agg_ln(const int* __restrict__ rowptr,
                                                const uint2* __restrict__ csr,
                                                const ushort_t* __restrict__ qf8,
                                                const uint_t* __restrict__ vb,
                                                const uint_t* __restrict__ ks,
                                                const float* __restrict__ We,
                                                const float* __restrict__ be,
                                                const float* __restrict__ gamma,
                                                const float* __restrict__ beta,
                                                ushort_t* __restrict__ hout)
{
    int tid = threadIdx.x;
    int lane = tid & 63;
    int node = __builtin_amdgcn_readfirstlane(blockIdx.x * 4 + (tid >> 6));
    int flo = ((lane >> 4) << 5) + (lane & 15);
    int fhi = flo + 16;

    f32x2 we2, be2, kd2, acc;
    we2.x = We[flo] * L2E; we2.y = We[fhi] * L2E;
    be2.x = be[flo] * L2E; be2.y = be[fhi] * L2E;
    uint_t klo = ks[(size_t)node * H + flo];
    uint_t khi = ks[(size_t)node * H + fhi];
    kd2.x = bf2f(klo & 0xffffu); kd2.y = bf2f(khi & 0xffffu);   // k' (·log2e)
    acc.x = bf2f(klo >> 16);     acc.y = bf2f(khi >> 16);       // h@Ws + b_gcn
    int p = rowptr[node];        // uniform -> s_load
    int pend = rowptr[node + 1];

#define GATH(QW, UV, A, C) { \
    A = __uint_as_float((C).y); \
    const ushort_t* qrow_ = qf8 + ((size_t)(C).x << 6); \
    const uint_t*   vrow_ = vb  + ((size_t)(C).x << 6); \
    QW = qrow_[lane]; \
    UV = vrow_[lane]; }

    while (p + 8 <= pend) {
        uint2 c0 = csr[p],     c1 = csr[p + 1], c2 = csr[p + 2], c3 = csr[p + 3];
        uint2 c4 = csr[p + 4], c5 = csr[p + 5], c6 = csr[p + 6], c7 = csr[p + 7];
        uint_t w0, w1, w2, w3, w4, w5, w6, w7;
        uint_t u0, u1, u2, u3, u4, u5, u6, u7;
        float a0, a1, a2, a3, a4, a5, a6, a7;
        GATH(w0, u0, a0, c0); GATH(w1, u1, a1, c1); GATH(w2, u2, a2, c2); GATH(w3, u3, a3, c3);
        GATH(w4, u4, a4, c4); GATH(w5, u5, a5, c5); GATH(w6, u6, a6, c6); GATH(w7, u7, a7, c7);
        edge_acc(w0, u0, a0, we2, be2, kd2, acc);
        edge_acc(w1, u1, a1, we2, be2, kd2, acc);
        edge_acc(w2, u2, a2, we2, be2, kd2, acc);
        edge_acc(w3, u3, a3, we2, be2, kd2, acc);
        edge_acc(w4, u4, a4, we2, be2, kd2, acc);
        edge_acc(w5, u5, a5, we2, be2, kd2, acc);
        edge_acc(w6, u6, a6, we2, be2, kd2, acc);
        edge_acc(w7, u7, a7, we2, be2, kd2, acc);
        p += 8;
    }
    if (p + 4 <= pend) {
        uint2 c0 = csr[p], c1 = csr[p + 1], c2 = csr[p + 2], c3 = csr[p + 3];
        uint_t w0, w1, w2, w3;
        uint_t u0, u1, u2, u3;
        float a0, a1, a2, a3;
        GATH(w0, u0, a0, c0); GATH(w1, u1, a1, c1); GATH(w2, u2, a2, c2); GATH(w3, u3, a3, c3);
        edge_acc(w0, u0, a0, we2, be2, kd2, acc);
        edge_acc(w1, u1, a1, we2, be2, kd2, acc);
        edge_acc(w2, u2, a2, we2, be2, kd2, acc);
        edge_acc(w3, u3, a3, we2, be2, kd2, acc);
        p += 4;
    }
    for (; p < pend; ++p) {
        uint2 c = csr[p];
        uint_t qw, uv; float a;
        GATH(qw, uv, a, c);
        edge_acc(qw, uv, a, we2, be2, kd2, acc);
    }
#undef GATH

    float s  = acc.x + acc.y;
    float s2 = acc.x * acc.x + acc.y * acc.y;
    #pragma unroll
    for (int off = 32; off > 0; off >>= 1) {
        s  += __shfl_down(s, off);
        s2 += __shfl_down(s2, off);
    }
    s  = __shfl(s, 0);
    s2 = __shfl(s2, 0);
    float mu  = s * (1.f / H);
    float var = s2 * (1.f / H) - mu * mu;
    float rstd = rsqrtf(var + EPSF);
    float glo = gamma[flo], ghi = gamma[fhi];
    float blo = beta[flo],  bhi = beta[fhi];
    float y0 = (acc.x - mu) * rstd * glo + blo;
    float y1 = (acc.y - mu) * rstd * ghi + bhi;
    y0 = 0.5f * y0 * (1.f + erff(y0 * 0.70710678118f));
    y1 = 0.5f * y1 * (1.f + erff(y1 * 0.70710678118f));
    hout[(size_t)node * H + flo] = f2bf(y0);
    hout[(size_t)node * H + fhi] = f2bf(y1);
}

// ---------------- out_proj MFMA: out = h @ W_out (fp32 out) ----------------
__global__ __launch_bounds__(256) void k_out_mfma(const ushort_t* __restrict__ hb,
                                                  const ushort_t* __restrict__ Bout, // [64][128]
                                                  float* __restrict__ out)
{
    int gw = blockIdx.x * 4 + (threadIdx.x >> 6);
    if (gw >= 6250) return;
    int lane = threadIdx.x & 63;
    int rg = gw >> 1, cg = gw & 1;
    int r0 = rg * 16, c0 = cg * 32;
    const ushort_t* Ap = hb + (size_t)(r0 + (lane & 15)) * H + 8 * (lane >> 4);
    const ushort_t* Bp = Bout + (size_t)(c0 + (lane & 15)) * H + 8 * (lane >> 4);
    f32x4 acc[2];
    acc[0] = (f32x4){0.f, 0.f, 0.f, 0.f};
    acc[1] = (f32x4){0.f, 0.f, 0.f, 0.f};
    #pragma unroll
    for (int kk = 0; kk < 4; ++kk) {
        bf16x8 a = *(const bf16x8*)(Ap + kk * 32);
        bf16x8 b0 = *(const bf16x8*)(Bp + kk * 32);
        bf16x8 b1 = *(const bf16x8*)(Bp + 16 * H + kk * 32);
        acc[0] = __builtin_amdgcn_mfma_f32_16x16x32_bf16(a, b0, acc[0], 0, 0, 0);
        acc[1] = __builtin_amdgcn_mfma_f32_16x16x32_bf16(a, b1, acc[1], 0, 0, 0);
    }
    int rowb = r0 + ((lane >> 4) << 2);
    #pragma unroll
    for (int nf = 0; nf < 2; ++nf) {
        int col = c0 + nf * 16 + (lane & 15);
        #pragma unroll
        for (int j = 0; j < 4; ++j)
            out[(size_t)(rowb + j) * DOUT + col] = acc[nf][j];
    }
}

extern "C" void kernel_launch(void* const* d_in, const int* in_sizes, int n_in,
                              void* d_out, int out_size, void* d_ws, size_t ws_size,
                              hipStream_t stream) {
    const float* x         = (const float*)d_in[0];
    const float* edge_attr = (const float*)d_in[1];
    const float* W_in      = (const float*)d_in[2];
    const float* b_in      = (const float*)d_in[3];
    const float* Wk        = (const float*)d_in[4];
    const float* bk        = (const float*)d_in[5];
    const float* Wq        = (const float*)d_in[6];
    const float* bq        = (const float*)d_in[7];
    const float* Wv        = (const float*)d_in[8];
    const float* bv        = (const float*)d_in[9];
    const float* We        = (const float*)d_in[10];
    const float* be        = (const float*)d_in[11];
    const float* Ws        = (const float*)d_in[12];
    const float* b_gcn     = (const float*)d_in[13];
    const float* gamma     = (const float*)d_in[14];
    const float* beta      = (const float*)d_in[15];
    const float* W_out     = (const float*)d_in[16];
    const int*   edge_index= (const int*)d_in[17];
    float* out = (float*)d_out;

    char* wsb = (char*)d_ws;
    ushort_t* hb  = (ushort_t*)wsb;                  wsb += (size_t)NPAD * H * 2;
    ushort_t* qf8 = (ushort_t*)wsb;                  wsb += (size_t)NPAD * 64 * 2;
    uint_t*   vb  = (uint_t*)wsb;                    wsb += (size_t)NPAD * 64 * 4;
    uint_t*   ks  = (uint_t*)wsb;                    wsb += (size_t)NPAD * H * 4;
    ushort_t* xb  = (ushort_t*)wsb;                  wsb += (size_t)NPAD * DIN * 2;
    ushort_t* Bq  = (ushort_t*)wsb;                  wsb += 3 * 512 * 128 * 2;
    ushort_t* Bin = (ushort_t*)wsb;                  wsb += 128 * 256 * 2;
    ushort_t* Bout= (ushort_t*)wsb;                  wsb += 64 * 128 * 2;
    uint2* csr    = (uint2*)wsb;                     wsb += (size_t)E_EDGES * 8;
    int*   rank   = (int*)wsb;                       wsb += (size_t)E_EDGES * 4;
    int*   deg8   = (int*)wsb;                       wsb += (size_t)NSHARD * N_NODES * 4;
    int*   rowptr = (int*)wsb;                       wsb += (N_NODES + 1) * 4;
    int*   bsum   = (int*)wsb;                       wsb += NBLK * 4;
    int*   boff   = (int*)wsb;                       wsb += NBLK * 4;

    (void)hipMemsetAsync(deg8, 0, (size_t)NSHARD * N_NODES * sizeof(int), stream);

    // fused: convx ∥ pack ∥ sharded hist(+rank)
    k_pre<<<CVB + PKB + HSB, 256, 0, stream>>>(x, xb, Wk, Wq, Wv, Ws, W_in, W_out,
                                               Bq, Bin, Bout, edge_index, deg8, rank);
    k_bsum<<<NBLK, 256, 0, stream>>>(deg8, bsum);
    k_bscan<<<1, 256, 0, stream>>>(bsum, boff);
    k_rowptr<<<NBLK, 256, 0, stream>>>(deg8, boff, rowptr);

    // fused: in_proj MFMA ∥ atomic-free CSR scatter
    k_mid<<<RT + SCB, 256, 0, stream>>>(xb, Bin, b_in, hb,
                                        edge_index, edge_attr, deg8, rank, csr);

    for (int l = 0; l < 3; ++l) {
        k_qkvs_mfma<<<2 * RT, 256, 0, stream>>>(hb, Bq + (size_t)l * 512 * 128,
                                                bk + l * H, bq + l * H, bv + l * H, b_gcn + l * H,
                                                qf8, vb, ks);
        k_agg_ln<<<N_NODES / 4, 256, 0, stream>>>(rowptr, csr, qf8, vb, ks,
                                                  We + l * H, be + l * H,
                                                  gamma + l * H, beta + l * H, hb);
    }
    k_out_mfma<<<RT, 256, 0, stream>>>(hb, Bout, out);
}

// Round 18
// 371.090 us; speedup vs baseline: 1.1522x; 1.0078x over previous
//
#include <hip/hip_runtime.h>

#define N_NODES 50000
#define NPAD    50048   // padded row count (multiple of 64) so 32-row tiles need no guard
#define E_EDGES 800000
#define DIN 256
#define H 128
#define DOUT 64
#define EPSF 1e-5f
#define NBLK 196   // ceil(N_NODES/256)
#define RT   1563  // ceil(N_NODES/32) row tiles
#define CVB  12500 // convx blocks
#define PKB  928   // pack blocks
#define HSB  3125  // hist blocks
#define NSHARD 8
#define SHARD_SZ 100000  // E_EDGES / NSHARD
#define SCHALF 391       // scatter blocks per half (1024 edges/block)
#define EHALF  400384    // SCHALF * 1024

typedef __bf16 bf16x8 __attribute__((ext_vector_type(8)));
typedef float  f32x4  __attribute__((ext_vector_type(4)));
typedef float  f32x2  __attribute__((ext_vector_type(2)));
typedef unsigned short ushort_t;
typedef unsigned int   uint_t;

#define L2E 1.4426950408889634f
#define LN2 0.6931471805599453f

#if __has_builtin(__builtin_amdgcn_exp2f)
#define EXP2F(x) __builtin_amdgcn_exp2f(x)
#else
#define EXP2F(x) __expf((x) * LN2)
#endif

__device__ inline float bf2f(uint_t u) {
    union { uint_t i; float f; } v; v.i = u << 16; return v.f;
}
__device__ inline ushort_t f2bf(float f) {
    uint_t u = __float_as_uint(f);
    uint_t r = (u + 0x7fffu + ((u >> 16) & 1u)) >> 16;
    return (ushort_t)r;
}

// ---- fp8 e4m3 helpers (hw path + software fallback) ----
#if __has_builtin(__builtin_amdgcn_cvt_f32_fp8)
#define FP8DEC(u, s) __builtin_amdgcn_cvt_f32_fp8((uint_t)(u), (s))
#else
__device__ inline float fp8_dec_sw(uint_t b) {
    uint_t s = (b & 0x80u) << 24;
    uint_t em = b & 0x7fu;
    if (em < 8u) return __uint_as_float(s);           // FTZ denormals
    uint_t ex = (em >> 3) + 120u;
    uint_t mn = (em & 7u) << 20;
    return __uint_as_float(s | (ex << 23) | mn);
}
#define FP8DEC(u, s) fp8_dec_sw(((uint_t)(u) >> (8 * (s))) & 0xffu)
#endif

// paired fp8 decode: 2 fp8 (low 16 bits) -> 2 floats
#if __has_builtin(__builtin_amdgcn_cvt_pk_f32_fp8)
__device__ __forceinline__ f32x2 cvtpk_q(uint_t u) {
    auto r = __builtin_amdgcn_cvt_pk_f32_fp8(u, false);
    f32x2 o; o.x = r[0]; o.y = r[1]; return o;
}
#else
__device__ __forceinline__ f32x2 cvtpk_q(uint_t u) {
    f32x2 r; r.x = FP8DEC(u, 0); r.y = FP8DEC(u, 1); return r;
}
#endif

#if __has_builtin(__builtin_amdgcn_cvt_pk_fp8_f32)
__device__ inline uint_t fp8_pk(float a, float b) {
    return (uint_t)__builtin_amdgcn_cvt_pk_fp8_f32(a, b, 0, false) & 0xffffu;
}
#else
__device__ inline uint_t fp8_enc_sw(float f) {
    uint_t u = __float_as_uint(f);
    uint_t s = (u >> 24) & 0x80u;
    uint_t a = u & 0x7fffffffu;
    if (a < 0x3c800000u) return s;           // |f| < 2^-6 -> 0
    if (a > 0x43e00000u) a = 0x43e00000u;    // clamp to 448
    uint_t r = a + 0x7ffffu + ((a >> 20) & 1u);
    uint_t ex = (r >> 23) - 120u;
    uint_t mn = (r >> 20) & 7u;
    return s | (ex << 3) | mn;
}
__device__ inline uint_t fp8_pk(float a, float b) {
    return fp8_enc_sw(a) | (fp8_enc_sw(b) << 8);
}
#endif

// ---- atomic-free CSR scatter, phase-split for max loads-in-flight ----
__device__ __forceinline__ void do_scatter4(int e0, const int* __restrict__ ei,
                                            const float* __restrict__ ea,
                                            const int* __restrict__ deg8,
                                            const int* __restrict__ rank,
                                            uint2* __restrict__ csr)
{
    int src[4], dst[4], rk[4];
    float a[4];
    bool ok[4];
    #pragma unroll
    for (int k = 0; k < 4; ++k) {
        int e = e0 + k * 256;
        ok[k] = e < E_EDGES;
        if (ok[k]) { src[k] = ei[e]; dst[k] = ei[E_EDGES + e]; a[k] = ea[e]; rk[k] = rank[e]; }
    }
    int pos[4];
    #pragma unroll
    for (int k = 0; k < 4; ++k)
        if (ok[k]) {
            int e = e0 + k * 256;
            pos[k] = deg8[(e / SHARD_SZ) * N_NODES + dst[k]] + rk[k];
        }
    #pragma unroll
    for (int k = 0; k < 4; ++k)
        if (ok[k]) csr[pos[k]] = make_uint2((uint_t)src[k], __float_as_uint(a[k]));
}

// ======= fused pre-pass: convx ∥ weight-pack ∥ sharded edge histogram =======
__global__ __launch_bounds__(256) void k_pre(const float* __restrict__ x, ushort_t* __restrict__ xb,
                                             const float* __restrict__ Wk, const float* __restrict__ Wq,
                                             const float* __restrict__ Wv, const float* __restrict__ Ws,
                                             const float* __restrict__ W_in, const float* __restrict__ W_out,
                                             ushort_t* __restrict__ Bq, ushort_t* __restrict__ Bin,
                                             ushort_t* __restrict__ Bout,
                                             const int* __restrict__ ei, int* __restrict__ deg8,
                                             int* __restrict__ rank)
{
    int b = blockIdx.x;
    int tid = threadIdx.x;
    if (b < CVB) {
        int i = b * 256 + tid;
        float4 v = ((const float4*)x)[i];
        ushort4 o;
        o.x = f2bf(v.x); o.y = f2bf(v.y); o.z = f2bf(v.z); o.w = f2bf(v.w);
        ((ushort4*)xb)[i] = o;
    } else if (b < CVB + PKB) {
        int t = (b - CVB) * 256 + tid;
        if (t < 196608) {
            int l = t >> 16;
            int r = t & 65535;
            int c = r >> 7;
            int k = r & 127;
            int m = c >> 7;
            int cm = c & 127;
            const float* W = (m == 0) ? Wk : (m == 1) ? Wq : (m == 2) ? Wv : Ws;
            Bq[t] = f2bf(W[(size_t)l * H * H + k * H + cm]);
        } else if (t < 229376) {
            int t2 = t - 196608;
            int c = t2 >> 8;
            int k = t2 & 255;
            Bin[t2] = f2bf(W_in[k * H + c]);
        } else {
            int t3 = t - 229376;
            int c = t3 >> 7;
            int k = t3 & 127;
            Bout[t3] = f2bf(W_out[k * DOUT + c]);
        }
    } else {
        int e = (b - CVB - PKB) * 256 + tid;
        int dst = ei[E_EDGES + e];
        int shard = e / SHARD_SZ;            // 8-way contention split
        rank[e] = atomicAdd(&deg8[shard * N_NODES + dst], 1);
    }
}

// ======= fused mid-pass: scatter half 0 (first) ∥ in_proj MFMA =======
__global__ __launch_bounds__(256) void k_mid(const ushort_t* __restrict__ xb,
                                             const ushort_t* __restrict__ Bin,
                                             const float* __restrict__ b_in,
                                             ushort_t* __restrict__ hb,
                                             const int* __restrict__ ei,
                                             const float* __restrict__ ea,
                                             const int* __restrict__ deg8,
                                             const int* __restrict__ rank,
                                             uint2* __restrict__ csr)
{
    int blk = blockIdx.x;
    int tid = threadIdx.x;
    if (blk < SCHALF) {
        do_scatter4(blk * 1024 + tid, ei, ea, deg8, rank, csr);
    } else {
        // ---- in_proj MFMA: 32 rows x 32 cols per wave, K=256 ----
        int gw = (blk - SCHALF) * 4 + (tid >> 6);
        int lane = tid & 63;
        int rt = gw >> 2, c32 = (gw & 3) * 32;
        int r0 = rt * 32;
        const ushort_t* Ap = xb + (size_t)(r0 + (lane & 15)) * DIN + 8 * (lane >> 4);
        const ushort_t* Bp = Bin + (size_t)(c32 + (lane & 15)) * DIN + 8 * (lane >> 4);
        f32x4 acc[2][2]; // [rb][nf]
        #pragma unroll
        for (int rb = 0; rb < 2; ++rb)
            #pragma unroll
            for (int nf = 0; nf < 2; ++nf) acc[rb][nf] = (f32x4){0.f, 0.f, 0.f, 0.f};
        #pragma unroll
        for (int ks = 0; ks < 8; ++ks) {
            bf16x8 a0 = *(const bf16x8*)(Ap + ks * 32);
            bf16x8 a1 = *(const bf16x8*)(Ap + 16 * DIN + ks * 32);
            bf16x8 b0 = *(const bf16x8*)(Bp + ks * 32);
            bf16x8 b1 = *(const bf16x8*)(Bp + 16 * DIN + ks * 32);
            acc[0][0] = __builtin_amdgcn_mfma_f32_16x16x32_bf16(a0, b0, acc[0][0], 0, 0, 0);
            acc[1][0] = __builtin_amdgcn_mfma_f32_16x16x32_bf16(a1, b0, acc[1][0], 0, 0, 0);
            acc[0][1] = __builtin_amdgcn_mfma_f32_16x16x32_bf16(a0, b1, acc[0][1], 0, 0, 0);
            acc[1][1] = __builtin_amdgcn_mfma_f32_16x16x32_bf16(a1, b1, acc[1][1], 0, 0, 0);
        }
        int rowoff = (lane >> 4) << 2;
        #pragma unroll
        for (int nf = 0; nf < 2; ++nf) {
            int col = c32 + nf * 16 + (lane & 15);
            float bb = b_in[col];
            #pragma unroll
            for (int rb = 0; rb < 2; ++rb)
                #pragma unroll
                for (int j = 0; j < 4; ++j)
                    hb[(size_t)(r0 + rb * 16 + rowoff + j) * H + col] = f2bf(acc[rb][nf][j] + bb);
        }
    }
}

// ------ qkvs MFMA (+ optional scatter blocks prepended, layer 0 only) ------
// pair 0 -> qf8 (fp8 q', 2/ushort) + vb (2 bf16 v / uint), entry e={f, f+16}
// pair 1 -> ks (uint: hi=agg bf16, lo=k' bf16), standard col index
__global__ __launch_bounds__(256) void k_qkvs_mfma(const ushort_t* __restrict__ hb,
                                                   const ushort_t* __restrict__ Bq, // [512][128]
                                                   const float* __restrict__ bk, const float* __restrict__ bq,
                                                   const float* __restrict__ bv, const float* __restrict__ bs,
                                                   ushort_t* __restrict__ qf8, uint_t* __restrict__ vb,
                                                   uint_t* __restrict__ ks,
                                                   const int* __restrict__ ei,
                                                   const float* __restrict__ ea,
                                                   const int* __restrict__ deg8,
                                                   const int* __restrict__ rank,
                                                   uint2* __restrict__ csr,
                                                   int scount, int sbase)
{
    int blk = blockIdx.x;
    int tid = threadIdx.x;
    if (blk < scount) {
        do_scatter4(sbase + blk * 1024 + tid, ei, ea, deg8, rank, csr);
        return;
    }
    int gw = (blk - scount) * 4 + (tid >> 6);
    int lane = tid & 63;
    int rt = gw >> 3, cfg = gw & 7;
    int pair = cfg >> 2, c32 = (cfg & 3) * 32;
    int r0 = rt * 32;
    const ushort_t* Ap = hb + (size_t)(r0 + (lane & 15)) * H + 8 * (lane >> 4);
    int cb0 = pair ? 0   : 128;   // k : q
    int cb1 = pair ? 384 : 256;   // s : v
    const ushort_t* Bp0 = Bq + (size_t)(cb0 + c32 + (lane & 15)) * H + 8 * (lane >> 4);
    const ushort_t* Bp1 = Bq + (size_t)(cb1 + c32 + (lane & 15)) * H + 8 * (lane >> 4);
    f32x4 acc[2][2][2]; // [rb][mat][nf]
    #pragma unroll
    for (int rb = 0; rb < 2; ++rb)
        #pragma unroll
        for (int m = 0; m < 2; ++m)
            #pragma unroll
            for (int nf = 0; nf < 2; ++nf) acc[rb][m][nf] = (f32x4){0.f, 0.f, 0.f, 0.f};
    #pragma unroll
    for (int kk = 0; kk < 4; ++kk) {
        bf16x8 a0 = *(const bf16x8*)(Ap + kk * 32);
        bf16x8 a1 = *(const bf16x8*)(Ap + 16 * H + kk * 32);
        #pragma unroll
        for (int nf = 0; nf < 2; ++nf) {
            bf16x8 b0 = *(const bf16x8*)(Bp0 + nf * 16 * H + kk * 32);
            bf16x8 b1 = *(const bf16x8*)(Bp1 + nf * 16 * H + kk * 32);
            acc[0][0][nf] = __builtin_amdgcn_mfma_f32_16x16x32_bf16(a0, b0, acc[0][0][nf], 0, 0, 0);
            acc[1][0][nf] = __builtin_amdgcn_mfma_f32_16x16x32_bf16(a1, b0, acc[1][0][nf], 0, 0, 0);
            acc[0][1][nf] = __builtin_amdgcn_mfma_f32_16x16x32_bf16(a0, b1, acc[0][1][nf], 0, 0, 0);
            acc[1][1][nf] = __builtin_amdgcn_mfma_f32_16x16x32_bf16(a1, b1, acc[1][1][nf], 0, 0, 0);
        }
    }
    int rowoff = (lane >> 4) << 2;
    int l15 = lane & 15;
    if (pair == 0) {
        int col_lo = c32 + l15, col_hi = col_lo + 16;
        int e = (c32 >> 1) + l15;
        float bql = bq[col_lo], bqh = bq[col_hi];
        float bvl = bv[col_lo], bvh = bv[col_hi];
        #pragma unroll
        for (int rb = 0; rb < 2; ++rb)
            #pragma unroll
            for (int j = 0; j < 4; ++j) {
                size_t row = r0 + rb * 16 + rowoff + j;
                float ql = (acc[rb][0][0][j] + bql) * L2E;
                float qh = (acc[rb][0][1][j] + bqh) * L2E;
                qf8[row * 64 + e] = (ushort_t)fp8_pk(ql, qh);
                uint_t vl = f2bf(acc[rb][1][0][j] + bvl);
                uint_t vh = f2bf(acc[rb][1][1][j] + bvh);
                vb[row * 64 + e] = (vh << 16) | vl;
            }
    } else {
        #pragma unroll
        for (int nf = 0; nf < 2; ++nf) {
            int col = c32 + nf * 16 + l15;
            float bbk = bk[col], bbs = bs[col];
            #pragma unroll
            for (int rb = 0; rb < 2; ++rb)
                #pragma unroll
                for (int j = 0; j < 4; ++j) {
                    size_t row = r0 + rb * 16 + rowoff + j;
                    uint_t kkv = f2bf((acc[rb][0][nf][j] + bbk) * L2E);
                    uint_t ssv = f2bf(acc[rb][1][nf][j] + bbs);
                    ks[row * H + col] = (ssv << 16) | kkv;
                }
        }
    }
}

// ================= CSR scan helpers (8-shard aware) =================
__global__ __launch_bounds__(256) void k_bsum(const int* __restrict__ deg8, int* __restrict__ bsum)
{
    __shared__ int ws[4];
    int t = threadIdx.x;
    int i = blockIdx.x * 256 + t;
    int v = 0;
    if (i < N_NODES) {
        #pragma unroll
        for (int s = 0; s < NSHARD; ++s) v += deg8[s * N_NODES + i];
    }
    #pragma unroll
    for (int off = 32; off > 0; off >>= 1) v += __shfl_down(v, off);
    if ((t & 63) == 0) ws[t >> 6] = v;
    __syncthreads();
    if (t == 0) bsum[blockIdx.x] = ws[0] + ws[1] + ws[2] + ws[3];
}

__global__ __launch_bounds__(256) void k_bscan(const int* __restrict__ bsum, int* __restrict__ boff)
{
    __shared__ int ws[4];
    int t = threadIdx.x;
    int v = (t < NBLK) ? bsum[t] : 0;
    int lane = t & 63, wid = t >> 6;
    int inc = v;
    #pragma unroll
    for (int off = 1; off < 64; off <<= 1) {
        int u = __shfl_up(inc, off);
        if (lane >= off) inc += u;
    }
    if (lane == 63) ws[wid] = inc;
    __syncthreads();
    if (t == 0) {
        int s = 0;
        #pragma unroll
        for (int w = 0; w < 4; ++w) { int x = ws[w]; ws[w] = s; s += x; }
    }
    __syncthreads();
    if (t < NBLK) boff[t] = inc - v + ws[wid];
}

// computes rowptr AND converts deg8 counts -> absolute per-shard bases in-place
__global__ __launch_bounds__(256) void k_rowptr(int* __restrict__ deg8,
                                                const int* __restrict__ boff,
                                                int* __restrict__ rowptr)
{
    __shared__ int ws[4];
    int t = threadIdx.x;
    int i = blockIdx.x * 256 + t;
    int d[NSHARD];
    int v = 0;
    if (i < N_NODES) {
        #pragma unroll
        for (int s = 0; s < NSHARD; ++s) { d[s] = deg8[s * N_NODES + i]; v += d[s]; }
    }
    int lane = t & 63, wid = t >> 6;
    int inc = v;
    #pragma unroll
    for (int off = 1; off < 64; off <<= 1) {
        int u = __shfl_up(inc, off);
        if (lane >= off) inc += u;
    }
    if (lane == 63) ws[wid] = inc;
    __syncthreads();
    if (t == 0) {
        int s = 0;
        #pragma unroll
        for (int w = 0; w < 4; ++w) { int x = ws[w]; ws[w] = s; s += x; }
    }
    __syncthreads();
    int excl = inc - v + ws[wid] + boff[blockIdx.x];
    if (i < N_NODES) {
        rowptr[i] = excl;
        int run = excl;
        #pragma unroll
        for (int s = 0; s < NSHARD; ++s) { int dd = d[s]; deg8[s * N_NODES + i] = run; run += dd; }
    }
    if (i == N_NODES - 1) rowptr[N_NODES] = excl + v;
}

// ---- per-edge gate+message (round-11 builtin math: best known good) ----
__device__ __forceinline__ void edge_acc(uint_t qw, uint_t uv, float ea,
                                         f32x2 we2, f32x2 be2, f32x2 kd2, f32x2& acc)
{
    f32x2 q = cvtpk_q(qw);
    f32x2 v;
    v.x = __uint_as_float(uv << 16);
    v.y = __uint_as_float(uv & 0xffff0000u);
    f32x2 av; av.x = ea; av.y = ea;
    f32x2 ep = __builtin_elementwise_fma(av, we2, be2);       // e' (·log2e)
    f32x2 g  = __builtin_elementwise_fma((f32x2){2.f, 2.f}, ep, kd2 + q);
    f32x2 ex; ex.x = EXP2F(-g.x); ex.y = EXP2F(-g.y);
    f32x2 d = ex + (f32x2){1.f, 1.f};
    f32x2 sg; sg.x = __builtin_amdgcn_rcpf(d.x); sg.y = __builtin_amdgcn_rcpf(d.y);
    f32x2 m = __builtin_elementwise_fma((f32x2){LN2, LN2}, ep, v); // v + e
    acc = __builtin_elementwise_fma(sg, m, acc);
}

// ===== aggregation (one wave per dst node) + LayerNorm + GELU -> h (bf16) =====
__global__ __launch_bounds__(256) void k_agg_ln(const int* __restrict__ rowptr,
                                                const uint2* __restrict__ csr,
                                                const ushort_t* __restrict__ qf8,
                                                const uint_t* __restrict__ vb,
                                                const uint_t* __restrict__ ks,
                                                const float* __restrict__ We,
                                                const float* __restrict__ be,
                                                const float* __restrict__ gamma,
                                                const float* __restrict__ beta,
                                                ushort_t* __restrict__ hout)
{
    int tid = threadIdx.x;
    int lane = tid & 63;
    int node = __builtin_amdgcn_readfirstlane(blockIdx.x * 4 + (tid >> 6));
    int flo = ((lane >> 4) << 5) + (lane & 15);
    int fhi = flo + 16;

    f32x2 we2, be2, kd2, acc;
    we2.x = We[flo] * L2E; we2.y = We[fhi] * L2E;
    be2.x = be[flo] * L2E; be2.y = be[fhi] * L2E;
    uint_t klo = ks[(size_t)node * H + flo];
    uint_t khi = ks[(size_t)node * H + fhi];
    kd2.x = bf2f(klo & 0xffffu); kd2.y = bf2f(khi & 0xffffu);   // k' (·log2e)
    acc.x = bf2f(klo >> 16);     acc.y = bf2f(khi >> 16);       // h@Ws + b_gcn
    int p = rowptr[node];        // uniform -> s_load
    int pend = rowptr[node + 1];

#define GATH(QW, UV, A, C) { \
    A = __uint_as_float((C).y); \
    const ushort_t* qrow_ = qf8 + ((size_t)(C).x << 6); \
    const uint_t*   vrow_ = vb  + ((size_t)(C).x << 6); \
    QW = qrow_[lane]; \
    UV = vrow_[lane]; }

    while (p + 8 <= pend) {
        uint2 c0 = csr[p],     c1 = csr[p + 1], c2 = csr[p + 2], c3 = csr[p + 3];
        uint2 c4 = csr[p + 4], c5 = csr[p + 5], c6 = csr[p + 6], c7 = csr[p + 7];
        uint_t w0, w1, w2, w3, w4, w5, w6, w7;
        uint_t u0, u1, u2, u3, u4, u5, u6, u7;
        float a0, a1, a2, a3, a4, a5, a6, a7;
        GATH(w0, u0, a0, c0); GATH(w1, u1, a1, c1); GATH(w2, u2, a2, c2); GATH(w3, u3, a3, c3);
        GATH(w4, u4, a4, c4); GATH(w5, u5, a5, c5); GATH(w6, u6, a6, c6); GATH(w7, u7, a7, c7);
        edge_acc(w0, u0, a0, we2, be2, kd2, acc);
        edge_acc(w1, u1, a1, we2, be2, kd2, acc);
        edge_acc(w2, u2, a2, we2, be2, kd2, acc);
        edge_acc(w3, u3, a3, we2, be2, kd2, acc);
        edge_acc(w4, u4, a4, we2, be2, kd2, acc);
        edge_acc(w5, u5, a5, we2, be2, kd2, acc);
        edge_acc(w6, u6, a6, we2, be2, kd2, acc);
        edge_acc(w7, u7, a7, we2, be2, kd2, acc);
        p += 8;
    }
    if (p + 4 <= pend) {
        uint2 c0 = csr[p], c1 = csr[p + 1], c2 = csr[p + 2], c3 = csr[p + 3];
        uint_t w0, w1, w2, w3;
        uint_t u0, u1, u2, u3;
        float a0, a1, a2, a3;
        GATH(w0, u0, a0, c0); GATH(w1, u1, a1, c1); GATH(w2, u2, a2, c2); GATH(w3, u3, a3, c3);
        edge_acc(w0, u0, a0, we2, be2, kd2, acc);
        edge_acc(w1, u1, a1, we2, be2, kd2, acc);
        edge_acc(w2, u2, a2, we2, be2, kd2, acc);
        edge_acc(w3, u3, a3, we2, be2, kd2, acc);
        p += 4;
    }
    for (; p < pend; ++p) {
        uint2 c = csr[p];
        uint_t qw, uv; float a;
        GATH(qw, uv, a, c);
        edge_acc(qw, uv, a, we2, be2, kd2, acc);
    }
#undef GATH

    float s  = acc.x + acc.y;
    float s2 = acc.x * acc.x + acc.y * acc.y;
    #pragma unroll
    for (int off = 32; off > 0; off >>= 1) {
        s  += __shfl_down(s, off);
        s2 += __shfl_down(s2, off);
    }
    s  = __shfl(s, 0);
    s2 = __shfl(s2, 0);
    float mu  = s * (1.f / H);
    float var = s2 * (1.f / H) - mu * mu;
    float rstd = rsqrtf(var + EPSF);
    float glo = gamma[flo], ghi = gamma[fhi];
    float blo = beta[flo],  bhi = beta[fhi];
    float y0 = (acc.x - mu) * rstd * glo + blo;
    float y1 = (acc.y - mu) * rstd * ghi + bhi;
    y0 = 0.5f * y0 * (1.f + erff(y0 * 0.70710678118f));
    y1 = 0.5f * y1 * (1.f + erff(y1 * 0.70710678118f));
    hout[(size_t)node * H + flo] = f2bf(y0);
    hout[(size_t)node * H + fhi] = f2bf(y1);
}

// ---------------- out_proj MFMA: out = h @ W_out (fp32 out) ----------------
__global__ __launch_bounds__(256) void k_out_mfma(const ushort_t* __restrict__ hb,
                                                  const ushort_t* __restrict__ Bout, // [64][128]
                                                  float* __restrict__ out)
{
    int gw = blockIdx.x * 4 + (threadIdx.x >> 6);
    if (gw >= 6250) return;
    int lane = threadIdx.x & 63;
    int rg = gw >> 1, cg = gw & 1;
    int r0 = rg * 16, c0 = cg * 32;
    const ushort_t* Ap = hb + (size_t)(r0 + (lane & 15)) * H + 8 * (lane >> 4);
    const ushort_t* Bp = Bout + (size_t)(c0 + (lane & 15)) * H + 8 * (lane >> 4);
    f32x4 acc[2];
    acc[0] = (f32x4){0.f, 0.f, 0.f, 0.f};
    acc[1] = (f32x4){0.f, 0.f, 0.f, 0.f};
    #pragma unroll
    for (int kk = 0; kk < 4; ++kk) {
        bf16x8 a = *(const bf16x8*)(Ap + kk * 32);
        bf16x8 b0 = *(const bf16x8*)(Bp + kk * 32);
        bf16x8 b1 = *(const bf16x8*)(Bp + 16 * H + kk * 32);
        acc[0] = __builtin_amdgcn_mfma_f32_16x16x32_bf16(a, b0, acc[0], 0, 0, 0);
        acc[1] = __builtin_amdgcn_mfma_f32_16x16x32_bf16(a, b1, acc[1], 0, 0, 0);
    }
    int rowb = r0 + ((lane >> 4) << 2);
    #pragma unroll
    for (int nf = 0; nf < 2; ++nf) {
        int col = c0 + nf * 16 + (lane & 15);
        #pragma unroll
        for (int j = 0; j < 4; ++j)
            out[(size_t)(rowb + j) * DOUT + col] = acc[nf][j];
    }
}

extern "C" void kernel_launch(void* const* d_in, const int* in_sizes, int n_in,
                              void* d_out, int out_size, void* d_ws, size_t ws_size,
                              hipStream_t stream) {
    const float* x         = (const float*)d_in[0];
    const float* edge_attr = (const float*)d_in[1];
    const float* W_in      = (const float*)d_in[2];
    const float* b_in      = (const float*)d_in[3];
    const float* Wk        = (const float*)d_in[4];
    const float* bk        = (const float*)d_in[5];
    const float* Wq        = (const float*)d_in[6];
    const float* bq        = (const float*)d_in[7];
    const float* Wv        = (const float*)d_in[8];
    const float* bv        = (const float*)d_in[9];
    const float* We        = (const float*)d_in[10];
    const float* be        = (const float*)d_in[11];
    const float* Ws        = (const float*)d_in[12];
    const float* b_gcn     = (const float*)d_in[13];
    const float* gamma     = (const float*)d_in[14];
    const float* beta      = (const float*)d_in[15];
    const float* W_out     = (const float*)d_in[16];
    const int*   edge_index= (const int*)d_in[17];
    float* out = (float*)d_out;

    char* wsb = (char*)d_ws;
    ushort_t* hb  = (ushort_t*)wsb;                  wsb += (size_t)NPAD * H * 2;
    ushort_t* qf8 = (ushort_t*)wsb;                  wsb += (size_t)NPAD * 64 * 2;
    uint_t*   vb  = (uint_t*)wsb;                    wsb += (size_t)NPAD * 64 * 4;
    uint_t*   ks  = (uint_t*)wsb;                    wsb += (size_t)NPAD * H * 4;
    ushort_t* xb  = (ushort_t*)wsb;                  wsb += (size_t)NPAD * DIN * 2;
    ushort_t* Bq  = (ushort_t*)wsb;                  wsb += 3 * 512 * 128 * 2;
    ushort_t* Bin = (ushort_t*)wsb;                  wsb += 128 * 256 * 2;
    ushort_t* Bout= (ushort_t*)wsb;                  wsb += 64 * 128 * 2;
    uint2* csr    = (uint2*)wsb;                     wsb += (size_t)E_EDGES * 8;
    int*   rank   = (int*)wsb;                       wsb += (size_t)E_EDGES * 4;
    int*   deg8   = (int*)wsb;                       wsb += (size_t)NSHARD * N_NODES * 4;
    int*   rowptr = (int*)wsb;                       wsb += (N_NODES + 1) * 4;
    int*   bsum   = (int*)wsb;                       wsb += NBLK * 4;
    int*   boff   = (int*)wsb;                       wsb += NBLK * 4;

    (void)hipMemsetAsync(deg8, 0, (size_t)NSHARD * N_NODES * sizeof(int), stream);

    // fused: convx ∥ pack ∥ sharded hist(+rank)
    k_pre<<<CVB + PKB + HSB, 256, 0, stream>>>(x, xb, Wk, Wq, Wv, Ws, W_in, W_out,
                                               Bq, Bin, Bout, edge_index, deg8, rank);
    k_bsum<<<NBLK, 256, 0, stream>>>(deg8, bsum);
    k_bscan<<<1, 256, 0, stream>>>(bsum, boff);
    k_rowptr<<<NBLK, 256, 0, stream>>>(deg8, boff, rowptr);

    // fused: scatter half 0 ∥ in_proj MFMA
    k_mid<<<SCHALF + RT, 256, 0, stream>>>(xb, Bin, b_in, hb,
                                           edge_index, edge_attr, deg8, rank, csr);

    for (int l = 0; l < 3; ++l) {
        int scount = (l == 0) ? SCHALF : 0;
        k_qkvs_mfma<<<scount + 2 * RT, 256, 0, stream>>>(hb, Bq + (size_t)l * 512 * 128,
                                                bk + l * H, bq + l * H, bv + l * H, b_gcn + l * H,
                                                qf8, vb, ks,
                                                edge_index, edge_attr, deg8, rank, csr,
                                                scount, EHALF);
        k_agg_ln<<<N_NODES / 4, 256, 0, stream>>>(rowptr, csr, qf8, vb, ks,
                                                  We + l * H, be + l * H,
                                                  gamma + l * H, beta + l * H, hb);
    }
    k_out_mfma<<<RT, 256, 0, stream>>>(hb, Bout, out);
}